// Round 4
// baseline (1847.981 us; speedup 1.0000x reference)
//
#include <hip/hip_runtime.h>
#include <hip/hip_bf16.h>
#include <math.h>

#define NN 50000
#define EE 500000
#define GG 1024
#define NDIM 32
#define EDIM 16
#define HH 128
#define LL 4
#define TILE 64    // edges per fused block
#define NTHR 512   // 8 waves
#define NBLK ((EE + TILE - 1) / TILE)   // 7813 (last block partial: 32 edges)
#define SCAN_NB ((NN + 255) / 256)      // 196

typedef unsigned short ushortT;
typedef __attribute__((ext_vector_type(8))) short bf16x8;   // 8 bf16 = 4 VGPR
typedef __attribute__((ext_vector_type(4))) float f32x4;    // MFMA C/D

#define MFMA16(a, b, c) __builtin_amdgcn_mfma_f32_16x16x32_bf16(a, b, c, 0, 0, 0)

__device__ inline float bf2f(ushortT u) {
    union { unsigned int i; float f; } v; v.i = ((unsigned int)u) << 16; return v.f;
}
__device__ inline ushortT f2bf(float f) {
    union { float f; unsigned int i; } v; v.f = f;
    unsigned int r = v.i + 0x7FFFu + ((v.i >> 16) & 1u);  // RNE
    return (ushortT)(r >> 16);
}
__device__ inline short f2bfs(float f) { return (short)f2bf(f); }

// Swizzled LDS A-fragment read: row-major bf16 tile, byte ^= (row&7)<<4 (T2)
__device__ inline bf16x8 lds_a(const char* base, int strideB, int row, int colByte) {
    int b = row * strideB + colByte;
    b ^= ((row & 7) << 4);
    return *reinterpret_cast<const bf16x8*>(base + b);
}

// ---------------- sort-by-dst (deterministic per call) ----------------
__global__ __launch_bounds__(256) void hist_kernel(
        const int* __restrict__ dst, int* __restrict__ counts) {
    int i = blockIdx.x * 256 + threadIdx.x;
    if (i < EE) atomicAdd(&counts[dst[i]], 1);
}

__global__ __launch_bounds__(256) void scan_part1(
        const int* __restrict__ counts, int* __restrict__ bsum) {
    __shared__ int buf[256];
    int t = threadIdx.x;
    int i = blockIdx.x * 256 + t;
    buf[t] = (i < NN) ? counts[i] : 0;
    __syncthreads();
    for (int s = 128; s > 0; s >>= 1) {
        if (t < s) buf[t] += buf[t + s];
        __syncthreads();
    }
    if (t == 0) bsum[blockIdx.x] = buf[0];
}

__global__ __launch_bounds__(256) void scan_part2(
        const int* __restrict__ bsum, int* __restrict__ bbase) {
    __shared__ int buf[256];
    int t = threadIdx.x;
    int v = (t < SCAN_NB) ? bsum[t] : 0;
    buf[t] = v;
    __syncthreads();
    for (int off = 1; off < 256; off <<= 1) {
        int s = (t >= off) ? buf[t - off] : 0;
        __syncthreads();
        buf[t] += s;
        __syncthreads();
    }
    if (t < SCAN_NB) bbase[t] = buf[t] - v;   // exclusive
}

__global__ __launch_bounds__(256) void scan_part3(
        const int* __restrict__ counts, const int* __restrict__ bbase,
        int* __restrict__ base) {
    __shared__ int buf[256];
    int t = threadIdx.x;
    int i = blockIdx.x * 256 + t;
    int v = (i < NN) ? counts[i] : 0;
    buf[t] = v;
    __syncthreads();
    for (int off = 1; off < 256; off <<= 1) {
        int s = (t >= off) ? buf[t - off] : 0;
        __syncthreads();
        buf[t] += s;
        __syncthreads();
    }
    if (i < NN) base[i] = bbase[blockIdx.x] + buf[t] - v;
}

__global__ __launch_bounds__(256) void build_perm_kernel(
        const int* __restrict__ src, const int* __restrict__ dst,
        const int* __restrict__ base, int* __restrict__ cnt,
        int* __restrict__ perm, int* __restrict__ srcS, int* __restrict__ dstS) {
    int i = blockIdx.x * 256 + threadIdx.x;
    if (i >= EE) return;
    int d = dst[i];
    int pos = base[d] + atomicAdd(&cnt[d], 1);
    perm[pos] = i;
    srcS[pos] = src[i];
    dstS[pos] = d;
}

// ---------------- weight prep: fp32 [K][N] -> bf16 [N][K], batched over L ----
__global__ __launch_bounds__(256) void transpose_kernel(
        const float* __restrict__ in, ushortT* __restrict__ out, int K, int N) {
    int per = K * N;
    int total = LL * per;
    int idx = blockIdx.x * 256 + threadIdx.x;
    if (idx >= total) return;
    int l = idx / per, rem = idx - l * per;
    int n = rem / K, k = rem - n * K;
    out[idx] = f2bf(in[(size_t)l * per + (size_t)k * N + n]);
}

// ---------------- embeds ----------------
__global__ __launch_bounds__(128) void node_embed_kernel(
        const float* __restrict__ x, const float* __restrict__ w,
        const float* __restrict__ b, float* __restrict__ h) {
    __shared__ float xs[NDIM];
    int i = blockIdx.x, j = threadIdx.x;
    if (j < NDIM) xs[j] = x[(size_t)i * NDIM + j];
    __syncthreads();
    float acc = b[j];
#pragma unroll
    for (int k = 0; k < NDIM; ++k) acc += xs[k] * w[k * HH + j];
    h[(size_t)i * HH + j] = acc;
}

// e_sorted[i] = embed(edge_attr[perm[i]]); 8 edges per 256-thread block
__global__ __launch_bounds__(256) void edge_embed_kernel(
        const float* __restrict__ ea, const int* __restrict__ perm,
        const float* __restrict__ w, const float* __restrict__ b,
        ushortT* __restrict__ e) {
    int i0 = blockIdx.x * 8;
    __shared__ int pidx[8];
    __shared__ float row[8][EDIM];
    int tid = threadIdx.x;
    if (tid < 8) pidx[tid] = perm[i0 + tid];
    __syncthreads();
    if (tid < 128) {
        int rr = tid >> 4, cc = tid & 15;
        row[rr][cc] = ea[(size_t)pidx[rr] * EDIM + cc];
    }
    __syncthreads();
    int cp = (tid & 63) * 2;
    int rb = tid >> 6;   // 0..3
#pragma unroll
    for (int s = 0; s < 2; ++s) {
        int rr = rb + 4 * s;
        float a0 = b[cp], a1 = b[cp + 1];
#pragma unroll
        for (int k = 0; k < EDIM; ++k) {
            float rv = row[rr][k];
            a0 += rv * w[k * HH + cp];
            a1 += rv * w[k * HH + cp + 1];
        }
        unsigned int pack = (unsigned int)f2bf(a0) | ((unsigned int)f2bf(a1) << 16);
        *reinterpret_cast<unsigned int*>(&e[(size_t)(i0 + rr) * HH + cp]) = pack;
    }
}

// ---------------- fused layer ----------------
// 8 waves as 2x4 grid: wave (wr,wc) owns rows wr*32+[0,32), cols wc*32+[0,32)
template<int K>
__device__ inline void gemm_phase(const char* aBase, int aStrideB, int aColByte,
        const ushortT* __restrict__ wT, const float* __restrict__ bias,
        int wr, int wc, int l15, int lg, f32x4 acc[2][2]) {
#pragma unroll
    for (int ntl = 0; ntl < 2; ++ntl) {
        float bb = bias[wc * 32 + ntl * 16 + l15];
        f32x4 iv = {bb, bb, bb, bb};
        acc[0][ntl] = iv;
        acc[1][ntl] = iv;
    }
#pragma unroll
    for (int ks = 0; ks < K / 32; ++ks) {
        int kk = ks * 32 + lg * 8;
        bf16x8 a0 = lds_a(aBase, aStrideB, wr * 32 + l15,      aColByte + kk * 2);
        bf16x8 a1 = lds_a(aBase, aStrideB, wr * 32 + 16 + l15, aColByte + kk * 2);
#pragma unroll
        for (int ntl = 0; ntl < 2; ++ntl) {
            int n = wc * 32 + ntl * 16 + l15;
            bf16x8 b = *reinterpret_cast<const bf16x8*>(wT + (size_t)n * K + kk);
            acc[0][ntl] = MFMA16(a0, b, acc[0][ntl]);
            acc[1][ntl] = MFMA16(a1, b, acc[1][ntl]);
        }
    }
}

__device__ inline void write_frag_bf16(char* base, int strideB, int colByteBase,
        int wr, int wc, int l15, int lg, f32x4 acc[2][2], bool relu) {
#pragma unroll
    for (int mt = 0; mt < 2; ++mt)
#pragma unroll
        for (int ntl = 0; ntl < 2; ++ntl) {
            int col = wc * 32 + ntl * 16 + l15;
#pragma unroll
            for (int r = 0; r < 4; ++r) {
                int row = wr * 32 + mt * 16 + lg * 4 + r;
                int b = row * strideB + colByteBase + col * 2;
                b ^= ((row & 7) << 4);
                float v = acc[mt][ntl][r];
                if (relu) v = fmaxf(v, 0.f);
                *reinterpret_cast<ushortT*>(base + b) = f2bf(v);
            }
        }
}

__global__ __launch_bounds__(NTHR) void fused_layer_kernel(
        const float* __restrict__ h, ushortT* __restrict__ e,
        const int* __restrict__ srcS, const int* __restrict__ dstS,
        const ushortT* __restrict__ ew1t, const float* __restrict__ eb1,
        const ushortT* __restrict__ ew2t, const float* __restrict__ eb2,
        const ushortT* __restrict__ nw1t, const float* __restrict__ nb1,
        const ushortT* __restrict__ nw2t, const float* __restrict__ nb2,
        const float* __restrict__ bng, const float* __restrict__ bnb,
        float inv_std, float* __restrict__ agg, int writeE) {
    __shared__ __align__(16) char catM[TILE * 512];   // [64][256] bf16 / msg [64][128] f32
    __shared__ __align__(16) char hidM[TILE * 256];   // [64][128] bf16
    __shared__ int sidx[TILE], dstx[TILE];
    int e0 = blockIdx.x * TILE;
    int V = EE - e0; if (V > TILE) V = TILE;
    int tid = threadIdx.x;
    if (tid < TILE) {
        int ii = e0 + tid;
        sidx[tid] = (ii < EE) ? srcS[ii] : 0;
        dstx[tid] = (ii < EE) ? dstS[ii] : -1;
    }
    __syncthreads();

    // stage e -> cat cols [128,256)
    for (int c = tid; c < TILE * 16; c += NTHR) {   // 16 chunks of 8 bf16 per row
        int row = c >> 4, col8 = (c & 15) * 8;
        bf16x8 v = {0, 0, 0, 0, 0, 0, 0, 0};
        if (row < V)
            v = *reinterpret_cast<const bf16x8*>(e + (size_t)(e0 + row) * HH + col8);
        int b = row * 512 + 256 + col8 * 2; b ^= ((row & 7) << 4);
        *reinterpret_cast<bf16x8*>(catM + b) = v;
    }
    // stage h[src] -> cat cols [0,128) (f32 -> bf16)
    for (int c = tid; c < TILE * 16; c += NTHR) {
        int row = c >> 4, col8 = (c & 15) * 8;
        bf16x8 o = {0, 0, 0, 0, 0, 0, 0, 0};
        if (row < V) {
            const float* hp = h + (size_t)sidx[row] * HH + col8;
            float4 va = *reinterpret_cast<const float4*>(hp);
            float4 vb = *reinterpret_cast<const float4*>(hp + 4);
            o[0] = f2bfs(va.x); o[1] = f2bfs(va.y); o[2] = f2bfs(va.z); o[3] = f2bfs(va.w);
            o[4] = f2bfs(vb.x); o[5] = f2bfs(vb.y); o[6] = f2bfs(vb.z); o[7] = f2bfs(vb.w);
        }
        int b = row * 512 + col8 * 2; b ^= ((row & 7) << 4);
        *reinterpret_cast<bf16x8*>(catM + b) = o;
    }
    __syncthreads();

    int wid = tid >> 6, lane = tid & 63;
    int wr = wid >> 2, wc = wid & 3;
    int l15 = lane & 15, lg = lane >> 4;
    f32x4 acc[2][2];

    // edge MLP phase 1: hid = relu(e @ ew1 + eb1), K=128 (A = cat cols 128..)
    gemm_phase<HH>(catM, 512, 256, ew1t, eb1, wr, wc, l15, lg, acc);
    write_frag_bf16(hidM, 256, 0, wr, wc, l15, lg, acc, true);
    __syncthreads();

    // edge MLP phase 2: e_new = hid @ ew2 + eb2 -> cat cols 128..
    gemm_phase<HH>(hidM, 256, 0, ew2t, eb2, wr, wc, l15, lg, acc);
    write_frag_bf16(catM, 512, 256, wr, wc, l15, lg, acc, false);
    __syncthreads();

    // copy e_new out (coalesced), except on the last layer
    if (writeE) {
        for (int c = tid; c < TILE * 16; c += NTHR) {
            int row = c >> 4, col8 = (c & 15) * 8;
            if (row < V) {
                int b = row * 512 + 256 + col8 * 2; b ^= ((row & 7) << 4);
                bf16x8 v = *reinterpret_cast<const bf16x8*>(catM + b);
                *reinterpret_cast<bf16x8*>(e + (size_t)(e0 + row) * HH + col8) = v;
            }
        }
    }

    // message phase 1: hid = relu(cat @ nw1 + nb1), K=256
    gemm_phase<2 * HH>(catM, 512, 0, nw1t, nb1, wr, wc, l15, lg, acc);
    write_frag_bf16(hidM, 256, 0, wr, wc, l15, lg, acc, true);  // safe: last hid readers synced
    __syncthreads();

    // message phase 2: msg = hid @ nw2 + nb2, BN, store f32 into catM [64][128]
    gemm_phase<HH>(hidM, 256, 0, nw2t, nb2, wr, wc, l15, lg, acc);
    float* msg = reinterpret_cast<float*>(catM);
#pragma unroll
    for (int ntl = 0; ntl < 2; ++ntl) {
        int col = wc * 32 + ntl * 16 + l15;
        float g = bng[col] * inv_std;
        float bb = bnb[col];
#pragma unroll
        for (int mt = 0; mt < 2; ++mt)
#pragma unroll
            for (int r = 0; r < 4; ++r) {
                int row = wr * 32 + mt * 16 + lg * 4 + r;
                msg[row * HH + col] = acc[mt][ntl][r] * g + bb;
            }
    }
    __syncthreads();

    // segmented reduction over sorted dst: 4 half-tiles of 16 rows
    int colT = tid & 127, half = tid >> 7;
    int rbeg = half * 16;
    int rend = rbeg + 16; if (rend > V) rend = V;
    if (rbeg < V) {
        float sum = 0.f;
        int dprev = dstx[rbeg];
        for (int r = rbeg; r < rend; ++r) {
            int d = dstx[r];
            float v = msg[r * HH + colT];
            if (d != dprev) {
                atomicAdd(&agg[(size_t)dprev * HH + colT], sum);
                sum = 0.f;
                dprev = d;
            }
            sum += v;
        }
        atomicAdd(&agg[(size_t)dprev * HH + colT], sum);
    }
}

// ---------------- pool + readout ----------------
__global__ __launch_bounds__(256) void pool_kernel(
        const float* __restrict__ h, const int* __restrict__ batch,
        float* __restrict__ pooled) {
    long long idx = (long long)blockIdx.x * 256 + threadIdx.x;
    if (idx >= (long long)NN * HH) return;
    int i = (int)(idx >> 7), c = (int)(idx & 127);
    atomicAdd(&pooled[(size_t)batch[i] * HH + c], h[idx]);
}

__global__ __launch_bounds__(128) void readout_kernel(
        const float* __restrict__ pooled,
        const float* __restrict__ w1, const float* __restrict__ b1,
        const float* __restrict__ w2, const float* __restrict__ b2,
        float* __restrict__ out) {
    __shared__ float row[HH];
    __shared__ float red[HH];
    int g = blockIdx.x, j = threadIdx.x;
    row[j] = pooled[(size_t)g * HH + j];
    __syncthreads();
    float acc = b1[j];
    for (int k = 0; k < HH; ++k) acc += row[k] * w1[k * HH + j];
    red[j] = fmaxf(acc, 0.f) * w2[j];
    __syncthreads();
    for (int s = 64; s > 0; s >>= 1) {
        if (j < s) red[j] += red[j + s];
        __syncthreads();
    }
    if (j == 0) out[g] = red[0] + b2[0];
}

extern "C" void kernel_launch(void* const* d_in, const int* in_sizes, int n_in,
                              void* d_out, int out_size, void* d_ws, size_t ws_size,
                              hipStream_t stream) {
    const float* x     = (const float*)d_in[0];
    const int*   ei    = (const int*)d_in[1];
    const float* ea    = (const float*)d_in[2];
    const int*   batch = (const int*)d_in[3];
    const float* ne_w  = (const float*)d_in[4];
    const float* ne_b  = (const float*)d_in[5];
    const float* ee_w  = (const float*)d_in[6];
    const float* ee_b  = (const float*)d_in[7];
    const float* nm_w1 = (const float*)d_in[8];
    const float* nm_b1 = (const float*)d_in[9];
    const float* nm_w2 = (const float*)d_in[10];
    const float* nm_b2 = (const float*)d_in[11];
    const float* bn_g  = (const float*)d_in[12];
    const float* bn_b  = (const float*)d_in[13];
    const float* em_w1 = (const float*)d_in[14];
    const float* em_b1 = (const float*)d_in[15];
    const float* em_w2 = (const float*)d_in[16];
    const float* em_b2 = (const float*)d_in[17];
    const float* ro_w1 = (const float*)d_in[18];
    const float* ro_b1 = (const float*)d_in[19];
    const float* ro_w2 = (const float*)d_in[20];
    const float* ro_b2 = (const float*)d_in[21];

    const int* srcp = ei;
    const int* dstp = ei + EE;

    // workspace carve (all 16B aligned)
    char* p = (char*)d_ws;
    float* h0 = (float*)p;       p += (size_t)NN * HH * 4;
    float* h1 = (float*)p;       p += (size_t)NN * HH * 4;
    float* pooled = (float*)p;   p += (size_t)GG * HH * 4;
    ushortT* ebuf = (ushortT*)p; p += (size_t)EE * HH * 2;
    ushortT* ew1t = (ushortT*)p; p += (size_t)LL * HH * HH * 2;
    ushortT* ew2t = (ushortT*)p; p += (size_t)LL * HH * HH * 2;
    ushortT* nw1t = (ushortT*)p; p += (size_t)LL * 2 * HH * HH * 2;
    ushortT* nw2t = (ushortT*)p; p += (size_t)LL * HH * HH * 2;
    int* perm   = (int*)p;       p += (size_t)EE * 4;
    int* srcS   = (int*)p;       p += (size_t)EE * 4;
    int* dstS   = (int*)p;       p += (size_t)EE * 4;
    int* counts = (int*)p;       p += (size_t)NN * 4;
    int* basep  = (int*)p;       p += (size_t)NN * 4;
    int* cnt    = (int*)p;       p += (size_t)NN * 4;
    int* bsum   = (int*)p;       p += (size_t)SCAN_NB * 4;
    int* bbase  = (int*)p;       p += (size_t)SCAN_NB * 4;

    // ---- sort edges by dst (deterministic recompute each call) ----
    hipMemsetAsync(counts, 0, (size_t)NN * 4, stream);
    hipMemsetAsync(cnt, 0, (size_t)NN * 4, stream);
    hist_kernel<<<(EE + 255) / 256, 256, 0, stream>>>(dstp, counts);
    scan_part1<<<SCAN_NB, 256, 0, stream>>>(counts, bsum);
    scan_part2<<<1, 256, 0, stream>>>(bsum, bbase);
    scan_part3<<<SCAN_NB, 256, 0, stream>>>(counts, bbase, basep);
    build_perm_kernel<<<(EE + 255) / 256, 256, 0, stream>>>(
        srcp, dstp, basep, cnt, perm, srcS, dstS);

    // ---- weight prep ----
    transpose_kernel<<<(LL * HH * HH + 255) / 256, 256, 0, stream>>>(em_w1, ew1t, HH, HH);
    transpose_kernel<<<(LL * HH * HH + 255) / 256, 256, 0, stream>>>(em_w2, ew2t, HH, HH);
    transpose_kernel<<<(LL * 2 * HH * HH + 255) / 256, 256, 0, stream>>>(nm_w1, nw1t, 2 * HH, HH);
    transpose_kernel<<<(LL * HH * HH + 255) / 256, 256, 0, stream>>>(nm_w2, nw2t, HH, HH);

    // ---- embeds ----
    node_embed_kernel<<<NN, 128, 0, stream>>>(x, ne_w, ne_b, h0);
    edge_embed_kernel<<<EE / 8, 256, 0, stream>>>(ea, perm, ee_w, ee_b, ebuf);

    // ---- layers ----
    const float inv_std = 1.0f / sqrtf(1.0f + 1e-5f);
    float* cur = h0;
    float* nxt = h1;
    for (int l = 0; l < LL; ++l) {
        hipMemcpyAsync(nxt, cur, sizeof(float) * (size_t)NN * HH,
                       hipMemcpyDeviceToDevice, stream);
        fused_layer_kernel<<<NBLK, NTHR, 0, stream>>>(
            cur, ebuf, srcS, dstS,
            ew1t + (size_t)l * HH * HH, em_b1 + l * HH,
            ew2t + (size_t)l * HH * HH, em_b2 + l * HH,
            nw1t + (size_t)l * 2 * HH * HH, nm_b1 + l * HH,
            nw2t + (size_t)l * HH * HH, nm_b2 + l * HH,
            bn_g + l * HH, bn_b + l * HH, inv_std, nxt,
            (l < LL - 1) ? 1 : 0);
        float* t = cur; cur = nxt; nxt = t;
    }

    // ---- pool + readout ----
    hipMemsetAsync(pooled, 0, sizeof(float) * (size_t)GG * HH, stream);
    {
        long long total = (long long)NN * HH;
        pool_kernel<<<(int)((total + 255) / 256), 256, 0, stream>>>(cur, batch, pooled);
    }
    readout_kernel<<<GG, 128, 0, stream>>>(pooled, ro_w1, ro_b1, ro_w2, ro_b2,
                                           (float*)d_out);
}

// Round 5
// 1501.834 us; speedup vs baseline: 1.2305x; 1.2305x over previous
//
#include <hip/hip_runtime.h>
#include <hip/hip_bf16.h>
#include <math.h>

#define NN 50000
#define EE 500000
#define GG 1024
#define NDIM 32
#define EDIM 16
#define HH 128
#define LL 4
#define TILE 64    // edges per fused block
#define NTHR 512   // 8 waves
#define NBLK ((EE + TILE - 1) / TILE)   // 7813 (last block partial: 32 edges)
#define SCAN_NB ((NN + 255) / 256)      // 196

typedef unsigned short ushortT;
typedef __attribute__((ext_vector_type(8))) short bf16x8;   // 8 bf16 = 4 VGPR
typedef __attribute__((ext_vector_type(4))) float f32x4;    // MFMA C/D

#define MFMA16(a, b, c) __builtin_amdgcn_mfma_f32_16x16x32_bf16(a, b, c, 0, 0, 0)

__device__ inline float bf2f(ushortT u) {
    union { unsigned int i; float f; } v; v.i = ((unsigned int)u) << 16; return v.f;
}
__device__ inline ushortT f2bf(float f) {
    union { float f; unsigned int i; } v; v.f = f;
    unsigned int r = v.i + 0x7FFFu + ((v.i >> 16) & 1u);  // RNE
    return (ushortT)(r >> 16);
}
__device__ inline short f2bfs(float f) { return (short)f2bf(f); }

// Swizzled LDS A-fragment read: row-major bf16 tile, byte ^= (row&mask)<<4 (T2)
__device__ inline bf16x8 lds_a(const char* base, int strideB, int row, int colByte,
                               int mask) {
    int b = row * strideB + colByte;
    b ^= ((row & mask) << 4);
    return *reinterpret_cast<const bf16x8*>(base + b);
}

// ---------------- sort-by-dst (deterministic per call) ----------------
__global__ __launch_bounds__(256) void hist_kernel(
        const int* __restrict__ dst, int* __restrict__ counts) {
    int i = blockIdx.x * 256 + threadIdx.x;
    if (i < EE) atomicAdd(&counts[dst[i]], 1);
}

__global__ __launch_bounds__(256) void scan_part1(
        const int* __restrict__ counts, int* __restrict__ bsum) {
    __shared__ int buf[256];
    int t = threadIdx.x;
    int i = blockIdx.x * 256 + t;
    buf[t] = (i < NN) ? counts[i] : 0;
    __syncthreads();
    for (int s = 128; s > 0; s >>= 1) {
        if (t < s) buf[t] += buf[t + s];
        __syncthreads();
    }
    if (t == 0) bsum[blockIdx.x] = buf[0];
}

__global__ __launch_bounds__(256) void scan_part2(
        const int* __restrict__ bsum, int* __restrict__ bbase) {
    __shared__ int buf[256];
    int t = threadIdx.x;
    int v = (t < SCAN_NB) ? bsum[t] : 0;
    buf[t] = v;
    __syncthreads();
    for (int off = 1; off < 256; off <<= 1) {
        int s = (t >= off) ? buf[t - off] : 0;
        __syncthreads();
        buf[t] += s;
        __syncthreads();
    }
    if (t < SCAN_NB) bbase[t] = buf[t] - v;   // exclusive
}

__global__ __launch_bounds__(256) void scan_part3(
        const int* __restrict__ counts, const int* __restrict__ bbase,
        int* __restrict__ base) {
    __shared__ int buf[256];
    int t = threadIdx.x;
    int i = blockIdx.x * 256 + t;
    int v = (i < NN) ? counts[i] : 0;
    buf[t] = v;
    __syncthreads();
    for (int off = 1; off < 256; off <<= 1) {
        int s = (t >= off) ? buf[t - off] : 0;
        __syncthreads();
        buf[t] += s;
        __syncthreads();
    }
    if (i < NN) base[i] = bbase[blockIdx.x] + buf[t] - v;
}

__global__ __launch_bounds__(256) void build_perm_kernel(
        const int* __restrict__ src, const int* __restrict__ dst,
        const int* __restrict__ base, int* __restrict__ cnt,
        int* __restrict__ perm, int* __restrict__ srcS, int* __restrict__ dstS) {
    int i = blockIdx.x * 256 + threadIdx.x;
    if (i >= EE) return;
    int d = dst[i];
    int pos = base[d] + atomicAdd(&cnt[d], 1);
    perm[pos] = i;
    srcS[pos] = src[i];
    dstS[pos] = d;
}

// ---------------- weight prep ----------------
// fp32 [K][N] -> bf16 [N][K], batched over L
__global__ __launch_bounds__(256) void transpose_kernel(
        const float* __restrict__ in, ushortT* __restrict__ out, int K, int N) {
    int per = K * N;
    int total = LL * per;
    int idx = blockIdx.x * 256 + threadIdx.x;
    if (idx >= total) return;
    int l = idx / per, rem = idx - l * per;
    int n = rem / K, k = rem - n * K;
    out[idx] = f2bf(in[(size_t)l * per + (size_t)k * N + n]);
}

// ee_w fp32 [16][128] -> bf16 [128][32], zero-padded k>=16
__global__ __launch_bounds__(256) void transpose_ee_kernel(
        const float* __restrict__ in, ushortT* __restrict__ out) {
    int idx = blockIdx.x * 256 + threadIdx.x;
    if (idx >= HH * 32) return;
    int n = idx >> 5, k = idx & 31;
    out[idx] = (k < EDIM) ? f2bf(in[k * HH + n]) : (ushortT)0;
}

// ---------------- node embed ----------------
__global__ __launch_bounds__(128) void node_embed_kernel(
        const float* __restrict__ x, const float* __restrict__ w,
        const float* __restrict__ b, float* __restrict__ h) {
    __shared__ float xs[NDIM];
    int i = blockIdx.x, j = threadIdx.x;
    if (j < NDIM) xs[j] = x[(size_t)i * NDIM + j];
    __syncthreads();
    float acc = b[j];
#pragma unroll
    for (int k = 0; k < NDIM; ++k) acc += xs[k] * w[k * HH + j];
    h[(size_t)i * HH + j] = acc;
}

// ---------------- fused layer ----------------
// 8 waves as 2x4 grid: wave (wr,wc) owns rows wr*32+[0,32), cols wc*32+[0,32)
template<int K>
__device__ inline void gemm_phase(const char* aBase, int aStrideB, int aColByte,
        int swzMask,
        const ushortT* __restrict__ wT, const float* __restrict__ bias,
        int wr, int wc, int l15, int lg, f32x4 acc[2][2]) {
#pragma unroll
    for (int ntl = 0; ntl < 2; ++ntl) {
        float bb = bias[wc * 32 + ntl * 16 + l15];
        f32x4 iv = {bb, bb, bb, bb};
        acc[0][ntl] = iv;
        acc[1][ntl] = iv;
    }
#pragma unroll
    for (int ks = 0; ks < K / 32; ++ks) {
        int kk = ks * 32 + lg * 8;
        bf16x8 a0 = lds_a(aBase, aStrideB, wr * 32 + l15,      aColByte + kk * 2, swzMask);
        bf16x8 a1 = lds_a(aBase, aStrideB, wr * 32 + 16 + l15, aColByte + kk * 2, swzMask);
#pragma unroll
        for (int ntl = 0; ntl < 2; ++ntl) {
            int n = wc * 32 + ntl * 16 + l15;
            bf16x8 b = *reinterpret_cast<const bf16x8*>(wT + (size_t)n * K + kk);
            acc[0][ntl] = MFMA16(a0, b, acc[0][ntl]);
            acc[1][ntl] = MFMA16(a1, b, acc[1][ntl]);
        }
    }
}

__device__ inline void write_frag_bf16(char* base, int strideB, int colByteBase,
        int wr, int wc, int l15, int lg, f32x4 acc[2][2], bool relu) {
#pragma unroll
    for (int mt = 0; mt < 2; ++mt)
#pragma unroll
        for (int ntl = 0; ntl < 2; ++ntl) {
            int col = wc * 32 + ntl * 16 + l15;
#pragma unroll
            for (int r = 0; r < 4; ++r) {
                int row = wr * 32 + mt * 16 + lg * 4 + r;
                int b = row * strideB + colByteBase + col * 2;
                b ^= ((row & 7) << 4);
                float v = acc[mt][ntl][r];
                if (relu) v = fmaxf(v, 0.f);
                *reinterpret_cast<ushortT*>(base + b) = f2bf(v);
            }
        }
}

template<int EMBED>
__global__ __launch_bounds__(NTHR) void fused_layer_kernel(
        const float* __restrict__ h, ushortT* __restrict__ e,
        const int* __restrict__ srcS, const int* __restrict__ dstS,
        const int* __restrict__ perm, const float* __restrict__ ea,
        const ushortT* __restrict__ eewT, const float* __restrict__ eeb,
        const ushortT* __restrict__ ew1t, const float* __restrict__ eb1,
        const ushortT* __restrict__ ew2t, const float* __restrict__ eb2,
        const ushortT* __restrict__ nw1t, const float* __restrict__ nb1,
        const ushortT* __restrict__ nw2t, const float* __restrict__ nb2,
        const float* __restrict__ bng, const float* __restrict__ bnb,
        float inv_std, float* __restrict__ agg, int writeE) {
    __shared__ __align__(16) char catM[TILE * 512];   // [64][256] bf16 / msg [64][128] f32
    __shared__ __align__(16) char hidM[TILE * 256];   // [64][128] bf16; also ea-tile [64][32]
    __shared__ int sidx[TILE], dstx[TILE], pidx[TILE];
    int e0 = blockIdx.x * TILE;
    int V = EE - e0; if (V > TILE) V = TILE;
    int tid = threadIdx.x;
    if (tid < TILE) {
        int ii = e0 + tid;
        sidx[tid] = (ii < EE) ? srcS[ii] : 0;
        dstx[tid] = (ii < EE) ? dstS[ii] : -1;
        if (EMBED) pidx[tid] = (ii < EE) ? perm[ii] : 0;
    }
    __syncthreads();

    if (EMBED) {
        // stage ea[perm] tile -> hidM as [64][32] bf16, zero-padded, swz mask 3
        for (int c = tid; c < TILE * 4; c += NTHR) {   // 256 float4 chunks
            int row = c >> 2, q4 = (c & 3) * 4;
            float4 v = make_float4(0.f, 0.f, 0.f, 0.f);
            if (row < V)
                v = *reinterpret_cast<const float4*>(ea + (size_t)pidx[row] * EDIM + q4);
            unsigned long long pack =
                (unsigned long long)f2bf(v.x) |
                ((unsigned long long)f2bf(v.y) << 16) |
                ((unsigned long long)f2bf(v.z) << 32) |
                ((unsigned long long)f2bf(v.w) << 48);
            int b = row * 64 + q4 * 2;
            b ^= ((row & 3) << 4);
            *reinterpret_cast<unsigned long long*>(hidM + b) = pack;
        }
        // zero-pad cols 16..31 (bytes 32..63)
        for (int c = tid; c < TILE * 2; c += NTHR) {
            int row = c >> 1;
            int b = row * 64 + 32 + (c & 1) * 16;
            b ^= ((row & 3) << 4);
            bf16x8 z = {0, 0, 0, 0, 0, 0, 0, 0};
            *reinterpret_cast<bf16x8*>(hidM + b) = z;
        }
    } else {
        // stage e -> cat cols [128,256)
        for (int c = tid; c < TILE * 16; c += NTHR) {   // 16 chunks of 8 bf16 per row
            int row = c >> 4, col8 = (c & 15) * 8;
            bf16x8 v = {0, 0, 0, 0, 0, 0, 0, 0};
            if (row < V)
                v = *reinterpret_cast<const bf16x8*>(e + (size_t)(e0 + row) * HH + col8);
            int b = row * 512 + 256 + col8 * 2; b ^= ((row & 7) << 4);
            *reinterpret_cast<bf16x8*>(catM + b) = v;
        }
    }
    // stage h[src] -> cat cols [0,128) (f32 -> bf16)
    for (int c = tid; c < TILE * 16; c += NTHR) {
        int row = c >> 4, col8 = (c & 15) * 8;
        bf16x8 o = {0, 0, 0, 0, 0, 0, 0, 0};
        if (row < V) {
            const float* hp = h + (size_t)sidx[row] * HH + col8;
            float4 va = *reinterpret_cast<const float4*>(hp);
            float4 vb = *reinterpret_cast<const float4*>(hp + 4);
            o[0] = f2bfs(va.x); o[1] = f2bfs(va.y); o[2] = f2bfs(va.z); o[3] = f2bfs(va.w);
            o[4] = f2bfs(vb.x); o[5] = f2bfs(vb.y); o[6] = f2bfs(vb.z); o[7] = f2bfs(vb.w);
        }
        int b = row * 512 + col8 * 2; b ^= ((row & 7) << 4);
        *reinterpret_cast<bf16x8*>(catM + b) = o;
    }
    __syncthreads();

    int wid = tid >> 6, lane = tid & 63;
    int wr = wid >> 2, wc = wid & 3;
    int l15 = lane & 15, lg = lane >> 4;
    f32x4 acc[2][2];

    if (EMBED) {
        // e0 = ea @ ee_w + ee_b (K=32 zero-padded) -> cat cols [128,256)
        gemm_phase<32>(hidM, 64, 0, 3, eewT, eeb, wr, wc, l15, lg, acc);
        write_frag_bf16(catM, 512, 256, wr, wc, l15, lg, acc, false);
        __syncthreads();
    }

    // edge MLP phase 1: hid = relu(e @ ew1 + eb1), K=128 (A = cat cols 128..)
    gemm_phase<HH>(catM, 512, 256, 7, ew1t, eb1, wr, wc, l15, lg, acc);
    write_frag_bf16(hidM, 256, 0, wr, wc, l15, lg, acc, true);
    __syncthreads();

    // edge MLP phase 2: e_new = hid @ ew2 + eb2 -> cat cols 128..
    gemm_phase<HH>(hidM, 256, 0, 7, ew2t, eb2, wr, wc, l15, lg, acc);
    write_frag_bf16(catM, 512, 256, wr, wc, l15, lg, acc, false);
    __syncthreads();

    // copy e_new out (coalesced), except on the last layer
    if (writeE) {
        for (int c = tid; c < TILE * 16; c += NTHR) {
            int row = c >> 4, col8 = (c & 15) * 8;
            if (row < V) {
                int b = row * 512 + 256 + col8 * 2; b ^= ((row & 7) << 4);
                bf16x8 v = *reinterpret_cast<const bf16x8*>(catM + b);
                *reinterpret_cast<bf16x8*>(e + (size_t)(e0 + row) * HH + col8) = v;
            }
        }
    }

    // message phase 1: hid = relu(cat @ nw1 + nb1), K=256
    gemm_phase<2 * HH>(catM, 512, 0, 7, nw1t, nb1, wr, wc, l15, lg, acc);
    write_frag_bf16(hidM, 256, 0, wr, wc, l15, lg, acc, true);  // safe: prior hid readers done
    __syncthreads();

    // message phase 2: msg = hid @ nw2 + nb2, BN, store f32 into catM [64][128]
    gemm_phase<HH>(hidM, 256, 0, 7, nw2t, nb2, wr, wc, l15, lg, acc);
    float* msg = reinterpret_cast<float*>(catM);
#pragma unroll
    for (int ntl = 0; ntl < 2; ++ntl) {
        int col = wc * 32 + ntl * 16 + l15;
        float g = bng[col] * inv_std;
        float bb = bnb[col];
#pragma unroll
        for (int mt = 0; mt < 2; ++mt)
#pragma unroll
            for (int r = 0; r < 4; ++r) {
                int row = wr * 32 + mt * 16 + lg * 4 + r;
                msg[row * HH + col] = acc[mt][ntl][r] * g + bb;
            }
    }
    __syncthreads();

    // segmented reduction over sorted dst: 4 half-tiles of 16 rows
    int colT = tid & 127, half = tid >> 7;
    int rbeg = half * 16;
    int rend = rbeg + 16; if (rend > V) rend = V;
    if (rbeg < V) {
        float sum = 0.f;
        int dprev = dstx[rbeg];
        for (int r = rbeg; r < rend; ++r) {
            int d = dstx[r];
            float v = msg[r * HH + colT];
            if (d != dprev) {
                atomicAdd(&agg[(size_t)dprev * HH + colT], sum);
                sum = 0.f;
                dprev = d;
            }
            sum += v;
        }
        atomicAdd(&agg[(size_t)dprev * HH + colT], sum);
    }
}

// ---------------- pool + readout ----------------
__global__ __launch_bounds__(256) void pool_kernel(
        const float* __restrict__ h, const int* __restrict__ batch,
        float* __restrict__ pooled) {
    long long idx = (long long)blockIdx.x * 256 + threadIdx.x;
    if (idx >= (long long)NN * HH) return;
    int i = (int)(idx >> 7), c = (int)(idx & 127);
    atomicAdd(&pooled[(size_t)batch[i] * HH + c], h[idx]);
}

__global__ __launch_bounds__(128) void readout_kernel(
        const float* __restrict__ pooled,
        const float* __restrict__ w1, const float* __restrict__ b1,
        const float* __restrict__ w2, const float* __restrict__ b2,
        float* __restrict__ out) {
    __shared__ float row[HH];
    __shared__ float red[HH];
    int g = blockIdx.x, j = threadIdx.x;
    row[j] = pooled[(size_t)g * HH + j];
    __syncthreads();
    float acc = b1[j];
    for (int k = 0; k < HH; ++k) acc += row[k] * w1[k * HH + j];
    red[j] = fmaxf(acc, 0.f) * w2[j];
    __syncthreads();
    for (int s = 64; s > 0; s >>= 1) {
        if (j < s) red[j] += red[j + s];
        __syncthreads();
    }
    if (j == 0) out[g] = red[0] + b2[0];
}

extern "C" void kernel_launch(void* const* d_in, const int* in_sizes, int n_in,
                              void* d_out, int out_size, void* d_ws, size_t ws_size,
                              hipStream_t stream) {
    const float* x     = (const float*)d_in[0];
    const int*   ei    = (const int*)d_in[1];
    const float* ea    = (const float*)d_in[2];
    const int*   batch = (const int*)d_in[3];
    const float* ne_w  = (const float*)d_in[4];
    const float* ne_b  = (const float*)d_in[5];
    const float* ee_w  = (const float*)d_in[6];
    const float* ee_b  = (const float*)d_in[7];
    const float* nm_w1 = (const float*)d_in[8];
    const float* nm_b1 = (const float*)d_in[9];
    const float* nm_w2 = (const float*)d_in[10];
    const float* nm_b2 = (const float*)d_in[11];
    const float* bn_g  = (const float*)d_in[12];
    const float* bn_b  = (const float*)d_in[13];
    const float* em_w1 = (const float*)d_in[14];
    const float* em_b1 = (const float*)d_in[15];
    const float* em_w2 = (const float*)d_in[16];
    const float* em_b2 = (const float*)d_in[17];
    const float* ro_w1 = (const float*)d_in[18];
    const float* ro_b1 = (const float*)d_in[19];
    const float* ro_w2 = (const float*)d_in[20];
    const float* ro_b2 = (const float*)d_in[21];

    const int* srcp = ei;
    const int* dstp = ei + EE;

    // workspace carve (all 16B aligned)
    char* p = (char*)d_ws;
    float* h0 = (float*)p;       p += (size_t)NN * HH * 4;
    float* h1 = (float*)p;       p += (size_t)NN * HH * 4;
    float* pooled = (float*)p;   p += (size_t)GG * HH * 4;
    ushortT* ebuf = (ushortT*)p; p += (size_t)EE * HH * 2;
    ushortT* ew1t = (ushortT*)p; p += (size_t)LL * HH * HH * 2;
    ushortT* ew2t = (ushortT*)p; p += (size_t)LL * HH * HH * 2;
    ushortT* nw1t = (ushortT*)p; p += (size_t)LL * 2 * HH * HH * 2;
    ushortT* nw2t = (ushortT*)p; p += (size_t)LL * HH * HH * 2;
    ushortT* eewT = (ushortT*)p; p += (size_t)HH * 32 * 2;
    int* perm   = (int*)p;       p += (size_t)EE * 4;
    int* srcS   = (int*)p;       p += (size_t)EE * 4;
    int* dstS   = (int*)p;       p += (size_t)EE * 4;
    int* counts = (int*)p;       p += (size_t)NN * 4;
    int* basep  = (int*)p;       p += (size_t)NN * 4;
    int* cnt    = (int*)p;       p += (size_t)NN * 4;
    int* bsum   = (int*)p;       p += (size_t)SCAN_NB * 4;
    int* bbase  = (int*)p;       p += (size_t)SCAN_NB * 4;

    // ---- sort edges by dst (deterministic recompute each call) ----
    hipMemsetAsync(counts, 0, (size_t)NN * 4, stream);
    hipMemsetAsync(cnt, 0, (size_t)NN * 4, stream);
    hist_kernel<<<(EE + 255) / 256, 256, 0, stream>>>(dstp, counts);
    scan_part1<<<SCAN_NB, 256, 0, stream>>>(counts, bsum);
    scan_part2<<<1, 256, 0, stream>>>(bsum, bbase);
    scan_part3<<<SCAN_NB, 256, 0, stream>>>(counts, bbase, basep);
    build_perm_kernel<<<(EE + 255) / 256, 256, 0, stream>>>(
        srcp, dstp, basep, cnt, perm, srcS, dstS);

    // ---- weight prep ----
    transpose_kernel<<<(LL * HH * HH + 255) / 256, 256, 0, stream>>>(em_w1, ew1t, HH, HH);
    transpose_kernel<<<(LL * HH * HH + 255) / 256, 256, 0, stream>>>(em_w2, ew2t, HH, HH);
    transpose_kernel<<<(LL * 2 * HH * HH + 255) / 256, 256, 0, stream>>>(nm_w1, nw1t, 2 * HH, HH);
    transpose_kernel<<<(LL * HH * HH + 255) / 256, 256, 0, stream>>>(nm_w2, nw2t, HH, HH);
    transpose_ee_kernel<<<(HH * 32 + 255) / 256, 256, 0, stream>>>(ee_w, eewT);

    // ---- node embed ----
    node_embed_kernel<<<NN, 128, 0, stream>>>(x, ne_w, ne_b, h0);

    // ---- layers (edge embed fused into layer 0) ----
    const float inv_std = 1.0f / sqrtf(1.0f + 1e-5f);
    float* cur = h0;
    float* nxt = h1;
    for (int l = 0; l < LL; ++l) {
        hipMemcpyAsync(nxt, cur, sizeof(float) * (size_t)NN * HH,
                       hipMemcpyDeviceToDevice, stream);
        if (l == 0) {
            fused_layer_kernel<1><<<NBLK, NTHR, 0, stream>>>(
                cur, ebuf, srcS, dstS, perm, ea, eewT, ee_b,
                ew1t + (size_t)l * HH * HH, em_b1 + l * HH,
                ew2t + (size_t)l * HH * HH, em_b2 + l * HH,
                nw1t + (size_t)l * 2 * HH * HH, nm_b1 + l * HH,
                nw2t + (size_t)l * HH * HH, nm_b2 + l * HH,
                bn_g + l * HH, bn_b + l * HH, inv_std, nxt,
                (l < LL - 1) ? 1 : 0);
        } else {
            fused_layer_kernel<0><<<NBLK, NTHR, 0, stream>>>(
                cur, ebuf, srcS, dstS, perm, ea, eewT, ee_b,
                ew1t + (size_t)l * HH * HH, em_b1 + l * HH,
                ew2t + (size_t)l * HH * HH, em_b2 + l * HH,
                nw1t + (size_t)l * 2 * HH * HH, nm_b1 + l * HH,
                nw2t + (size_t)l * HH * HH, nm_b2 + l * HH,
                bn_g + l * HH, bn_b + l * HH, inv_std, nxt,
                (l < LL - 1) ? 1 : 0);
        }
        float* t = cur; cur = nxt; nxt = t;
    }

    // ---- pool + readout ----
    hipMemsetAsync(pooled, 0, sizeof(float) * (size_t)GG * HH, stream);
    {
        long long total = (long long)NN * HH;
        pool_kernel<<<(int)((total + 255) / 256), 256, 0, stream>>>(cur, batch, pooled);
    }
    readout_kernel<<<GG, 128, 0, stream>>>(pooled, ro_w1, ro_b1, ro_w2, ro_b2,
                                           (float*)d_out);
}

// Round 6
// 1222.446 us; speedup vs baseline: 1.5117x; 1.2285x over previous
//
#include <hip/hip_runtime.h>
#include <hip/hip_bf16.h>
#include <math.h>

#define NN 50000
#define EE 500000
#define GG 1024
#define NDIM 32
#define EDIM 16
#define HH 128
#define LL 4
#define TILE 64
#define NTHR 512
#define NT ((EE + TILE - 1) / TILE)     // 7813 tiles (last V=32)
#define PBLK 768                        // persistent blocks (3/CU)
#define NPB ((NN + 63) / 64)            // node_pre blocks
#define SCAN_NB ((NN + 255) / 256)

typedef unsigned short ushortT;
typedef __attribute__((ext_vector_type(8))) short bf16x8;
typedef __attribute__((ext_vector_type(4))) float f32x4;

#define MFMA16(a, b, c) __builtin_amdgcn_mfma_f32_16x16x32_bf16(a, b, c, 0, 0, 0)

__device__ inline float bf2f(ushortT u) {
    union { unsigned int i; float f; } v; v.i = ((unsigned int)u) << 16; return v.f;
}
__device__ inline ushortT f2bf(float f) {
    union { float f; unsigned int i; } v; v.f = f;
    unsigned int r = v.i + 0x7FFFu + ((v.i >> 16) & 1u);  // RNE
    return (ushortT)(r >> 16);
}
__device__ inline short f2bfs(float f) { return (short)f2bf(f); }

__device__ inline bf16x8 lds_a(const char* base, int strideB, int row, int colByte,
                               int mask) {
    int b = row * strideB + colByte;
    b ^= ((row & mask) << 4);
    return *reinterpret_cast<const bf16x8*>(base + b);
}

// ---------------- sort-by-dst ----------------
__global__ __launch_bounds__(256) void hist_kernel(
        const int* __restrict__ dst, int* __restrict__ counts) {
    int i = blockIdx.x * 256 + threadIdx.x;
    if (i < EE) atomicAdd(&counts[dst[i]], 1);
}

__global__ __launch_bounds__(256) void scan_part1(
        const int* __restrict__ counts, int* __restrict__ bsum) {
    __shared__ int buf[256];
    int t = threadIdx.x;
    int i = blockIdx.x * 256 + t;
    buf[t] = (i < NN) ? counts[i] : 0;
    __syncthreads();
    for (int s = 128; s > 0; s >>= 1) {
        if (t < s) buf[t] += buf[t + s];
        __syncthreads();
    }
    if (t == 0) bsum[blockIdx.x] = buf[0];
}

__global__ __launch_bounds__(256) void scan_part2(
        const int* __restrict__ bsum, int* __restrict__ bbase) {
    __shared__ int buf[256];
    int t = threadIdx.x;
    int v = (t < SCAN_NB) ? bsum[t] : 0;
    buf[t] = v;
    __syncthreads();
    for (int off = 1; off < 256; off <<= 1) {
        int s = (t >= off) ? buf[t - off] : 0;
        __syncthreads();
        buf[t] += s;
        __syncthreads();
    }
    if (t < SCAN_NB) bbase[t] = buf[t] - v;
}

__global__ __launch_bounds__(256) void scan_part3(
        const int* __restrict__ counts, const int* __restrict__ bbase,
        int* __restrict__ base) {
    __shared__ int buf[256];
    int t = threadIdx.x;
    int i = blockIdx.x * 256 + t;
    int v = (i < NN) ? counts[i] : 0;
    buf[t] = v;
    __syncthreads();
    for (int off = 1; off < 256; off <<= 1) {
        int s = (t >= off) ? buf[t - off] : 0;
        __syncthreads();
        buf[t] += s;
        __syncthreads();
    }
    if (i < NN) base[i] = bbase[blockIdx.x] + buf[t] - v;
}

__global__ __launch_bounds__(256) void build_perm_kernel(
        const int* __restrict__ src, const int* __restrict__ dst,
        const int* __restrict__ base, int* __restrict__ cnt,
        int* __restrict__ perm, int* __restrict__ srcS, int* __restrict__ dstS) {
    int i = blockIdx.x * 256 + threadIdx.x;
    if (i >= EE) return;
    int d = dst[i];
    int pos = base[d] + atomicAdd(&cnt[d], 1);
    perm[pos] = i;
    srcS[pos] = src[i];
    dstS[pos] = d;
}

// ---------------- weight prep ----------------
__global__ __launch_bounds__(256) void transpose_kernel(
        const float* __restrict__ in, ushortT* __restrict__ out, int K, int N) {
    int per = K * N;
    int total = LL * per;
    int idx = blockIdx.x * 256 + threadIdx.x;
    if (idx >= total) return;
    int l = idx / per, rem = idx - l * per;
    int n = rem / K, k = rem - n * K;
    out[idx] = f2bf(in[(size_t)l * per + (size_t)k * N + n]);
}

__global__ __launch_bounds__(256) void transpose_ee_kernel(
        const float* __restrict__ in, ushortT* __restrict__ out) {
    int idx = blockIdx.x * 256 + threadIdx.x;
    if (idx >= HH * 32) return;
    int n = idx >> 5, k = idx & 31;
    out[idx] = (k < EDIM) ? f2bf(in[k * HH + n]) : (ushortT)0;
}

// ---------------- node embed ----------------
__global__ __launch_bounds__(128) void node_embed_kernel(
        const float* __restrict__ x, const float* __restrict__ w,
        const float* __restrict__ b, float* __restrict__ h) {
    __shared__ float xs[NDIM];
    int i = blockIdx.x, j = threadIdx.x;
    if (j < NDIM) xs[j] = x[(size_t)i * NDIM + j];
    __syncthreads();
    float acc = b[j];
#pragma unroll
    for (int k = 0; k < NDIM; ++k) acc += xs[k] * w[k * HH + j];
    h[(size_t)i * HH + j] = acc;
}

// ---------------- GEMM helpers (8 waves, 2x4 grid, 64x128 tile) ----------------
template<int K, int KS>
__device__ inline void gemm_bias(const char* aBase, int aStrideB, int aColByte,
        int mask, const ushortT* __restrict__ wT, const float* __restrict__ bias,
        int wr, int wc, int l15, int lg, f32x4 acc[2][2]) {
#pragma unroll
    for (int ntl = 0; ntl < 2; ++ntl) {
        float bb = bias[wc * 32 + ntl * 16 + l15];
        f32x4 iv = {bb, bb, bb, bb};
        acc[0][ntl] = iv;
        acc[1][ntl] = iv;
    }
#pragma unroll
    for (int ks = 0; ks < K / 32; ++ks) {
        int kk = ks * 32 + lg * 8;
        bf16x8 a0 = lds_a(aBase, aStrideB, wr * 32 + l15,      aColByte + kk * 2, mask);
        bf16x8 a1 = lds_a(aBase, aStrideB, wr * 32 + 16 + l15, aColByte + kk * 2, mask);
#pragma unroll
        for (int ntl = 0; ntl < 2; ++ntl) {
            int n = wc * 32 + ntl * 16 + l15;
            bf16x8 b = *reinterpret_cast<const bf16x8*>(wT + (size_t)n * KS + kk);
            acc[0][ntl] = MFMA16(a0, b, acc[0][ntl]);
            acc[1][ntl] = MFMA16(a1, b, acc[1][ntl]);
        }
    }
}

// nm1': C-init from uT (bf16 [64][128] swz7), A = eT, B = nw1t cols, k-offset 128
__device__ inline void gemm_uinit(const char* aBase, const char* uBase,
        const ushortT* __restrict__ wT,
        int wr, int wc, int l15, int lg, f32x4 acc[2][2]) {
#pragma unroll
    for (int mt = 0; mt < 2; ++mt)
#pragma unroll
        for (int ntl = 0; ntl < 2; ++ntl) {
            int col = wc * 32 + ntl * 16 + l15;
#pragma unroll
            for (int r = 0; r < 4; ++r) {
                int row = wr * 32 + mt * 16 + lg * 4 + r;
                int b = row * 256 + col * 2; b ^= ((row & 7) << 4);
                acc[mt][ntl][r] = bf2f(*reinterpret_cast<const ushortT*>(uBase + b));
            }
        }
#pragma unroll
    for (int ks = 0; ks < 4; ++ks) {
        int kk = ks * 32 + lg * 8;
        bf16x8 a0 = lds_a(aBase, 256, wr * 32 + l15,      kk * 2, 7);
        bf16x8 a1 = lds_a(aBase, 256, wr * 32 + 16 + l15, kk * 2, 7);
#pragma unroll
        for (int ntl = 0; ntl < 2; ++ntl) {
            int n = wc * 32 + ntl * 16 + l15;
            bf16x8 b = *reinterpret_cast<const bf16x8*>(wT + (size_t)n * 256 + 128 + kk);
            acc[0][ntl] = MFMA16(a0, b, acc[0][ntl]);
            acc[1][ntl] = MFMA16(a1, b, acc[1][ntl]);
        }
    }
}

__device__ inline void write_frag_bf16(char* base, int wr, int wc, int l15, int lg,
                                       f32x4 acc[2][2], bool relu) {
#pragma unroll
    for (int mt = 0; mt < 2; ++mt)
#pragma unroll
        for (int ntl = 0; ntl < 2; ++ntl) {
            int col = wc * 32 + ntl * 16 + l15;
#pragma unroll
            for (int r = 0; r < 4; ++r) {
                int row = wr * 32 + mt * 16 + lg * 4 + r;
                int b = row * 256 + col * 2;
                b ^= ((row & 7) << 4);
                float v = acc[mt][ntl][r];
                if (relu) v = fmaxf(v, 0.f);
                *reinterpret_cast<ushortT*>(base + b) = f2bf(v);
            }
        }
}

// ---------------- node_pre: u = h @ W1a + b1 (bf16 out) ; also copy h -> hcopy ----
__global__ __launch_bounds__(NTHR) void node_pre_kernel(
        const float* __restrict__ h, const ushortT* __restrict__ w1t,
        const float* __restrict__ b1, ushortT* __restrict__ u,
        float* __restrict__ hcopy) {
    __shared__ __align__(16) char hT[TILE * 256];
    int base = blockIdx.x * TILE;
    int V = NN - base; if (V > TILE) V = TILE;
    int tid = threadIdx.x;
    int c1 = tid + NTHR;
    int r0 = tid >> 4, r1 = c1 >> 4;
    int q0 = (tid & 15) * 8, q1 = (c1 & 15) * 8;
#pragma unroll
    for (int s = 0; s < 2; ++s) {
        int rr = s ? r1 : r0, qq = s ? q1 : q0;
        bf16x8 o = {0, 0, 0, 0, 0, 0, 0, 0};
        if (rr < V) {
            const float* hp = h + (size_t)(base + rr) * HH + qq;
            float4 va = *reinterpret_cast<const float4*>(hp);
            float4 vb = *reinterpret_cast<const float4*>(hp + 4);
            float* cp = hcopy + (size_t)(base + rr) * HH + qq;
            *reinterpret_cast<float4*>(cp) = va;
            *reinterpret_cast<float4*>(cp + 4) = vb;
            o[0] = f2bfs(va.x); o[1] = f2bfs(va.y); o[2] = f2bfs(va.z); o[3] = f2bfs(va.w);
            o[4] = f2bfs(vb.x); o[5] = f2bfs(vb.y); o[6] = f2bfs(vb.z); o[7] = f2bfs(vb.w);
        }
        int b = rr * 256 + qq * 2; b ^= ((rr & 7) << 4);
        *reinterpret_cast<bf16x8*>(hT + b) = o;
    }
    __syncthreads();
    int wid = tid >> 6, lane = tid & 63;
    int wr = wid >> 2, wc = wid & 3, l15 = lane & 15, lg = lane >> 4;
    f32x4 acc[2][2];
    gemm_bias<HH, 2 * HH>(hT, 256, 0, 7, w1t, b1, wr, wc, l15, lg, acc);
    __syncthreads();
    write_frag_bf16(hT, wr, wc, l15, lg, acc, false);
    __syncthreads();
#pragma unroll
    for (int s = 0; s < 2; ++s) {
        int rr = s ? r1 : r0, qq = s ? q1 : q0;
        if (rr < V) {
            int b = rr * 256 + qq * 2; b ^= ((rr & 7) << 4);
            *reinterpret_cast<bf16x8*>(u + (size_t)(base + rr) * HH + qq) =
                *reinterpret_cast<const bf16x8*>(hT + b);
        }
    }
}

// ---------------- fused layer (pipelined, persistent grid-stride) ----------------
template<int EMBED, int LASTL>
__global__ __launch_bounds__(NTHR) void fused_layer_kernel(
        const ushortT* __restrict__ u, ushortT* __restrict__ e,
        const int* __restrict__ srcS, const int* __restrict__ dstS,
        const int* __restrict__ perm, const float* __restrict__ ea,
        const ushortT* __restrict__ eewT, const float* __restrict__ eeb,
        const ushortT* __restrict__ ew1t, const float* __restrict__ eb1,
        const ushortT* __restrict__ ew2t, const float* __restrict__ eb2,
        const ushortT* __restrict__ nw1t,
        const ushortT* __restrict__ nw2t, const float* __restrict__ nb2,
        const float* __restrict__ bng, const float* __restrict__ bnb,
        float inv_std, float* __restrict__ agg) {
    __shared__ __align__(16) char eT[TILE * 256];    // [64][128] bf16 swz7
    __shared__ __align__(16) char uT[TILE * 256];    // [64][128] bf16 swz7
    __shared__ __align__(16) char hidM[TILE * 256];  // [64][128] bf16 swz7; eaT in [0,4K) swz3
    __shared__ int dstx[TILE];

    const int tid = threadIdx.x;
    const int wid = tid >> 6, lane = tid & 63;
    const int wr = wid >> 2, wc = wid & 3, l15 = lane & 15, lg = lane >> 4;
    const int c1 = tid + NTHR;
    const int r0 = tid >> 4, r1 = c1 >> 4;
    const int q0 = (tid & 15) * 8, q1 = (c1 & 15) * 8;
    const bf16x8 z8 = {0, 0, 0, 0, 0, 0, 0, 0};

    // prefetch registers
    bf16x8 pu0 = z8, pu1 = z8, pe0 = z8, pe1 = z8;
    float4 pea = make_float4(0.f, 0.f, 0.f, 0.f);
    int pdst = -1;

    int t = blockIdx.x;
    {   // initial loads for tile t
        int base = t * TILE;
        if (tid < TILE) pdst = (base + tid < EE) ? dstS[base + tid] : -1;
        int s0 = (base + r0 < EE) ? srcS[base + r0] : 0;
        int s1 = (base + r1 < EE) ? srcS[base + r1] : 0;
        if (base + r0 < EE) pu0 = *reinterpret_cast<const bf16x8*>(u + (size_t)s0 * HH + q0);
        if (base + r1 < EE) pu1 = *reinterpret_cast<const bf16x8*>(u + (size_t)s1 * HH + q1);
        if (EMBED) {
            if (tid < TILE * 4) {
                int prow = tid >> 2, pq = (tid & 3) * 4;
                if (base + prow < EE) {
                    int pp = perm[base + prow];
                    pea = *reinterpret_cast<const float4*>(ea + (size_t)pp * EDIM + pq);
                }
            }
        } else {
            if (base + r0 < EE) pe0 = *reinterpret_cast<const bf16x8*>(e + (size_t)(base + r0) * HH + q0);
            if (base + r1 < EE) pe1 = *reinterpret_cast<const bf16x8*>(e + (size_t)(base + r1) * HH + q1);
        }
    }

    for (; t < NT; t += PBLK) {
        const int base = t * TILE;
        int V = EE - base; if (V > TILE) V = TILE;

        __syncthreads();   // previous iteration's LDS readers done
        // ---- stage tile t from regs ----
        if (tid < TILE) dstx[tid] = pdst;
        { int b = r0 * 256 + q0 * 2; b ^= ((r0 & 7) << 4); *reinterpret_cast<bf16x8*>(uT + b) = pu0; }
        { int b = r1 * 256 + q1 * 2; b ^= ((r1 & 7) << 4); *reinterpret_cast<bf16x8*>(uT + b) = pu1; }
        if (EMBED) {
            if (tid < TILE * 4) {
                int prow = tid >> 2, pq = (tid & 3) * 4;
                unsigned long long pack =
                    (unsigned long long)f2bf(pea.x) |
                    ((unsigned long long)f2bf(pea.y) << 16) |
                    ((unsigned long long)f2bf(pea.z) << 32) |
                    ((unsigned long long)f2bf(pea.w) << 48);
                int b = prow * 64 + pq * 2; b ^= ((prow & 3) << 4);
                *reinterpret_cast<unsigned long long*>(hidM + b) = pack;
            }
            if (tid < TILE * 2) {
                int prow = tid >> 1;
                int b = prow * 64 + 32 + (tid & 1) * 16; b ^= ((prow & 3) << 4);
                *reinterpret_cast<bf16x8*>(hidM + b) = z8;
            }
        } else {
            { int b = r0 * 256 + q0 * 2; b ^= ((r0 & 7) << 4); *reinterpret_cast<bf16x8*>(eT + b) = pe0; }
            { int b = r1 * 256 + q1 * 2; b ^= ((r1 & 7) << 4); *reinterpret_cast<bf16x8*>(eT + b) = pe1; }
        }
        // ---- issue next tile's loads (overlap with compute below) ----
        {
            const int tn = t + PBLK;
            if (tn < NT) {
                const int bn = tn * TILE;
                pdst = -1;
                if (tid < TILE) pdst = (bn + tid < EE) ? dstS[bn + tid] : -1;
                int s0 = (bn + r0 < EE) ? srcS[bn + r0] : 0;
                int s1 = (bn + r1 < EE) ? srcS[bn + r1] : 0;
                pu0 = z8; pu1 = z8;
                if (bn + r0 < EE) pu0 = *reinterpret_cast<const bf16x8*>(u + (size_t)s0 * HH + q0);
                if (bn + r1 < EE) pu1 = *reinterpret_cast<const bf16x8*>(u + (size_t)s1 * HH + q1);
                if (EMBED) {
                    pea = make_float4(0.f, 0.f, 0.f, 0.f);
                    if (tid < TILE * 4) {
                        int prow = tid >> 2, pq = (tid & 3) * 4;
                        if (bn + prow < EE) {
                            int pp = perm[bn + prow];
                            pea = *reinterpret_cast<const float4*>(ea + (size_t)pp * EDIM + pq);
                        }
                    }
                } else {
                    pe0 = z8; pe1 = z8;
                    if (bn + r0 < EE) pe0 = *reinterpret_cast<const bf16x8*>(e + (size_t)(bn + r0) * HH + q0);
                    if (bn + r1 < EE) pe1 = *reinterpret_cast<const bf16x8*>(e + (size_t)(bn + r1) * HH + q1);
                }
            }
        }
        __syncthreads();   // staging visible

        f32x4 acc[2][2];
        if (EMBED) {
            // e0 = ea @ ee_w + ee_b (K=32 zero-padded) -> eT
            gemm_bias<32, 32>(hidM, 64, 0, 3, eewT, eeb, wr, wc, l15, lg, acc);
            write_frag_bf16(eT, wr, wc, l15, lg, acc, false);
            __syncthreads();
        }
        // em1: hid = relu(e @ ew1 + eb1)
        gemm_bias<HH, HH>(eT, 256, 0, 7, ew1t, eb1, wr, wc, l15, lg, acc);
        write_frag_bf16(hidM, wr, wc, l15, lg, acc, true);
        __syncthreads();
        // em2: e_new = hid @ ew2 + eb2 -> eT
        gemm_bias<HH, HH>(hidM, 256, 0, 7, ew2t, eb2, wr, wc, l15, lg, acc);
        write_frag_bf16(eT, wr, wc, l15, lg, acc, false);
        __syncthreads();
        // e_new copy-out (skip last layer)
        if (!LASTL) {
#pragma unroll
            for (int s = 0; s < 2; ++s) {
                int rr = s ? r1 : r0, qq = s ? q1 : q0;
                if (rr < V) {
                    int b = rr * 256 + qq * 2; b ^= ((rr & 7) << 4);
                    *reinterpret_cast<bf16x8*>(e + (size_t)(base + rr) * HH + qq) =
                        *reinterpret_cast<const bf16x8*>(eT + b);
                }
            }
        }
        // nm1': hid = relu(u_src + e_new @ W1b)
        gemm_uinit(eT, uT, nw1t, wr, wc, l15, lg, acc);
        write_frag_bf16(hidM, wr, wc, l15, lg, acc, true);
        __syncthreads();
        // nm2: msg = hid @ nw2 + nb2 ; BN + in-register segmented reduce
        gemm_bias<HH, HH>(hidM, 256, 0, 7, nw2t, nb2, wr, wc, l15, lg, acc);
#pragma unroll
        for (int ntl = 0; ntl < 2; ++ntl) {
            int col = wc * 32 + ntl * 16 + l15;
            float g = bng[col] * inv_std;
            float bb = bnb[col];
#pragma unroll
            for (int mt = 0; mt < 2; ++mt) {
                int lr0 = wr * 32 + mt * 16 + lg * 4;
                if (lr0 < V) {
                    float sum = 0.f;
                    int dprev = dstx[lr0];
#pragma unroll
                    for (int r = 0; r < 4; ++r) {
                        int lr = lr0 + r;
                        if (lr < V) {
                            int d = dstx[lr];
                            float m = acc[mt][ntl][r] * g + bb;
                            if (d != dprev) {
                                atomicAdd(&agg[(size_t)dprev * HH + col], sum);
                                sum = 0.f;
                                dprev = d;
                            }
                            sum += m;
                        }
                    }
                    atomicAdd(&agg[(size_t)dprev * HH + col], sum);
                }
            }
        }
    }
}

// ---------------- pool + readout ----------------
__global__ __launch_bounds__(256) void pool_kernel(
        const float* __restrict__ h, const int* __restrict__ batch,
        float* __restrict__ pooled) {
    long long idx = (long long)blockIdx.x * 256 + threadIdx.x;
    if (idx >= (long long)NN * HH) return;
    int i = (int)(idx >> 7), c = (int)(idx & 127);
    atomicAdd(&pooled[(size_t)batch[i] * HH + c], h[idx]);
}

__global__ __launch_bounds__(128) void readout_kernel(
        const float* __restrict__ pooled,
        const float* __restrict__ w1, const float* __restrict__ b1,
        const float* __restrict__ w2, const float* __restrict__ b2,
        float* __restrict__ out) {
    __shared__ float row[HH];
    __shared__ float red[HH];
    int g = blockIdx.x, j = threadIdx.x;
    row[j] = pooled[(size_t)g * HH + j];
    __syncthreads();
    float acc = b1[j];
    for (int k = 0; k < HH; ++k) acc += row[k] * w1[k * HH + j];
    red[j] = fmaxf(acc, 0.f) * w2[j];
    __syncthreads();
    for (int s = 64; s > 0; s >>= 1) {
        if (j < s) red[j] += red[j + s];
        __syncthreads();
    }
    if (j == 0) out[g] = red[0] + b2[0];
}

extern "C" void kernel_launch(void* const* d_in, const int* in_sizes, int n_in,
                              void* d_out, int out_size, void* d_ws, size_t ws_size,
                              hipStream_t stream) {
    const float* x     = (const float*)d_in[0];
    const int*   ei    = (const int*)d_in[1];
    const float* ea    = (const float*)d_in[2];
    const int*   batch = (const int*)d_in[3];
    const float* ne_w  = (const float*)d_in[4];
    const float* ne_b  = (const float*)d_in[5];
    const float* ee_w  = (const float*)d_in[6];
    const float* ee_b  = (const float*)d_in[7];
    const float* nm_w1 = (const float*)d_in[8];
    const float* nm_b1 = (const float*)d_in[9];
    const float* nm_w2 = (const float*)d_in[10];
    const float* nm_b2 = (const float*)d_in[11];
    const float* bn_g  = (const float*)d_in[12];
    const float* bn_b  = (const float*)d_in[13];
    const float* em_w1 = (const float*)d_in[14];
    const float* em_b1 = (const float*)d_in[15];
    const float* em_w2 = (const float*)d_in[16];
    const float* em_b2 = (const float*)d_in[17];
    const float* ro_w1 = (const float*)d_in[18];
    const float* ro_b1 = (const float*)d_in[19];
    const float* ro_w2 = (const float*)d_in[20];
    const float* ro_b2 = (const float*)d_in[21];

    const int* srcp = ei;
    const int* dstp = ei + EE;

    // workspace carve (16B aligned)
    char* p = (char*)d_ws;
    float* h0 = (float*)p;       p += (size_t)NN * HH * 4;
    float* h1 = (float*)p;       p += (size_t)NN * HH * 4;
    float* pooled = (float*)p;   p += (size_t)GG * HH * 4;
    ushortT* ebuf = (ushortT*)p; p += (size_t)EE * HH * 2;
    ushortT* ubuf = (ushortT*)p; p += (size_t)NN * HH * 2;
    ushortT* ew1t = (ushortT*)p; p += (size_t)LL * HH * HH * 2;
    ushortT* ew2t = (ushortT*)p; p += (size_t)LL * HH * HH * 2;
    ushortT* nw1t = (ushortT*)p; p += (size_t)LL * 2 * HH * HH * 2;
    ushortT* nw2t = (ushortT*)p; p += (size_t)LL * HH * HH * 2;
    ushortT* eewT = (ushortT*)p; p += (size_t)HH * 32 * 2;
    int* perm   = (int*)p;       p += (size_t)EE * 4;
    int* srcS   = (int*)p;       p += (size_t)EE * 4;
    int* dstS   = (int*)p;       p += (size_t)EE * 4;
    int* counts = (int*)p;       p += (size_t)NN * 4;
    int* basep  = (int*)p;       p += (size_t)NN * 4;
    int* cnt    = (int*)p;       p += (size_t)NN * 4;
    int* bsum   = (int*)p;       p += (size_t)SCAN_NB * 4;
    int* bbase  = (int*)p;       p += (size_t)SCAN_NB * 4;

    // ---- sort edges by dst ----
    hipMemsetAsync(counts, 0, (size_t)NN * 4, stream);
    hipMemsetAsync(cnt, 0, (size_t)NN * 4, stream);
    hist_kernel<<<(EE + 255) / 256, 256, 0, stream>>>(dstp, counts);
    scan_part1<<<SCAN_NB, 256, 0, stream>>>(counts, bsum);
    scan_part2<<<1, 256, 0, stream>>>(bsum, bbase);
    scan_part3<<<SCAN_NB, 256, 0, stream>>>(counts, bbase, basep);
    build_perm_kernel<<<(EE + 255) / 256, 256, 0, stream>>>(
        srcp, dstp, basep, cnt, perm, srcS, dstS);

    // ---- weight prep ----
    transpose_kernel<<<(LL * HH * HH + 255) / 256, 256, 0, stream>>>(em_w1, ew1t, HH, HH);
    transpose_kernel<<<(LL * HH * HH + 255) / 256, 256, 0, stream>>>(em_w2, ew2t, HH, HH);
    transpose_kernel<<<(LL * 2 * HH * HH + 255) / 256, 256, 0, stream>>>(nm_w1, nw1t, 2 * HH, HH);
    transpose_kernel<<<(LL * HH * HH + 255) / 256, 256, 0, stream>>>(nm_w2, nw2t, HH, HH);
    transpose_ee_kernel<<<(HH * 32 + 255) / 256, 256, 0, stream>>>(ee_w, eewT);

    // ---- node embed ----
    node_embed_kernel<<<NN, 128, 0, stream>>>(x, ne_w, ne_b, h0);

    // ---- layers ----
    const float inv_std = 1.0f / sqrtf(1.0f + 1e-5f);
    float* cur = h0;
    float* nxt = h1;
    for (int l = 0; l < LL; ++l) {
        // u = h @ W1a + b1 ; nxt = copy(h)
        node_pre_kernel<<<NPB, NTHR, 0, stream>>>(
            cur, nw1t + (size_t)l * 2 * HH * HH, nm_b1 + l * HH, ubuf, nxt);
        if (l == 0) {
            fused_layer_kernel<1, 0><<<PBLK, NTHR, 0, stream>>>(
                ubuf, ebuf, srcS, dstS, perm, ea, eewT, ee_b,
                ew1t + (size_t)l * HH * HH, em_b1 + l * HH,
                ew2t + (size_t)l * HH * HH, em_b2 + l * HH,
                nw1t + (size_t)l * 2 * HH * HH,
                nw2t + (size_t)l * HH * HH, nm_b2 + l * HH,
                bn_g + l * HH, bn_b + l * HH, inv_std, nxt);
        } else if (l < LL - 1) {
            fused_layer_kernel<0, 0><<<PBLK, NTHR, 0, stream>>>(
                ubuf, ebuf, srcS, dstS, perm, ea, eewT, ee_b,
                ew1t + (size_t)l * HH * HH, em_b1 + l * HH,
                ew2t + (size_t)l * HH * HH, em_b2 + l * HH,
                nw1t + (size_t)l * 2 * HH * HH,
                nw2t + (size_t)l * HH * HH, nm_b2 + l * HH,
                bn_g + l * HH, bn_b + l * HH, inv_std, nxt);
        } else {
            fused_layer_kernel<0, 1><<<PBLK, NTHR, 0, stream>>>(
                ubuf, ebuf, srcS, dstS, perm, ea, eewT, ee_b,
                ew1t + (size_t)l * HH * HH, em_b1 + l * HH,
                ew2t + (size_t)l * HH * HH, em_b2 + l * HH,
                nw1t + (size_t)l * 2 * HH * HH,
                nw2t + (size_t)l * HH * HH, nm_b2 + l * HH,
                bn_g + l * HH, bn_b + l * HH, inv_std, nxt);
        }
        float* t = cur; cur = nxt; nxt = t;
    }

    // ---- pool + readout ----
    hipMemsetAsync(pooled, 0, sizeof(float) * (size_t)GG * HH, stream);
    {
        long long total = (long long)NN * HH;
        pool_kernel<<<(int)((total + 255) / 256), 256, 0, stream>>>(cur, batch, pooled);
    }
    readout_kernel<<<GG, 128, 0, stream>>>(pooled, ro_w1, ro_b1, ro_w2, ro_b2,
                                           (float*)d_out);
}

// Round 7
// 1196.026 us; speedup vs baseline: 1.5451x; 1.0221x over previous
//
#include <hip/hip_runtime.h>
#include <hip/hip_bf16.h>
#include <math.h>

#define NN 50000
#define EE 500000
#define GG 1024
#define NDIM 32
#define EDIM 16
#define HH 128
#define LL 4
#define NT2 ((EE + 127) / 128)    // 3907 edge tiles (last V=32)
#define NB2 ((NN + 127) / 128)    // 391 node tiles (last V=80)
#define SCAN_NB ((NN + 255) / 256)

typedef unsigned short ushortT;
typedef __attribute__((ext_vector_type(8))) short bf16x8;
typedef __attribute__((ext_vector_type(4))) float f32x4;

#define MFMA16(a, b, c) __builtin_amdgcn_mfma_f32_16x16x32_bf16(a, b, c, 0, 0, 0)

__device__ inline float bf2f(ushortT u) {
    union { unsigned int i; float f; } v; v.i = ((unsigned int)u) << 16; return v.f;
}
__device__ inline ushortT f2bf(float f) {
    union { float f; unsigned int i; } v; v.f = f;
    unsigned int r = v.i + 0x7FFFu + ((v.i >> 16) & 1u);  // RNE
    return (ushortT)(r >> 16);
}
__device__ inline short f2bfs(float f) { return (short)f2bf(f); }

__device__ inline bf16x8 lds_a(const char* base, int strideB, int row, int colByte,
                               int mask) {
    int b = row * strideB + colByte;
    b ^= ((row & mask) << 4);
    return *reinterpret_cast<const bf16x8*>(base + b);
}

// ---------------- sort-by-dst ----------------
__global__ __launch_bounds__(256) void hist_kernel(
        const int* __restrict__ dst, int* __restrict__ counts) {
    int i = blockIdx.x * 256 + threadIdx.x;
    if (i < EE) atomicAdd(&counts[dst[i]], 1);
}

__global__ __launch_bounds__(256) void scan_part1(
        const int* __restrict__ counts, int* __restrict__ bsum) {
    __shared__ int buf[256];
    int t = threadIdx.x;
    int i = blockIdx.x * 256 + t;
    buf[t] = (i < NN) ? counts[i] : 0;
    __syncthreads();
    for (int s = 128; s > 0; s >>= 1) {
        if (t < s) buf[t] += buf[t + s];
        __syncthreads();
    }
    if (t == 0) bsum[blockIdx.x] = buf[0];
}

__global__ __launch_bounds__(256) void scan_part2(
        const int* __restrict__ bsum, int* __restrict__ bbase) {
    __shared__ int buf[256];
    int t = threadIdx.x;
    int v = (t < SCAN_NB) ? bsum[t] : 0;
    buf[t] = v;
    __syncthreads();
    for (int off = 1; off < 256; off <<= 1) {
        int s = (t >= off) ? buf[t - off] : 0;
        __syncthreads();
        buf[t] += s;
        __syncthreads();
    }
    if (t < SCAN_NB) bbase[t] = buf[t] - v;
}

__global__ __launch_bounds__(256) void scan_part3(
        const int* __restrict__ counts, const int* __restrict__ bbase,
        int* __restrict__ base) {
    __shared__ int buf[256];
    int t = threadIdx.x;
    int i = blockIdx.x * 256 + t;
    int v = (i < NN) ? counts[i] : 0;
    buf[t] = v;
    __syncthreads();
    for (int off = 1; off < 256; off <<= 1) {
        int s = (t >= off) ? buf[t - off] : 0;
        __syncthreads();
        buf[t] += s;
        __syncthreads();
    }
    if (i < NN) base[i] = bbase[blockIdx.x] + buf[t] - v;
}

__global__ __launch_bounds__(256) void build_perm_kernel(
        const int* __restrict__ src, const int* __restrict__ dst,
        const int* __restrict__ base, int* __restrict__ cnt,
        int* __restrict__ perm, int* __restrict__ srcS, int* __restrict__ dstS) {
    int i = blockIdx.x * 256 + threadIdx.x;
    if (i >= EE) return;
    int d = dst[i];
    int pos = base[d] + atomicAdd(&cnt[d], 1);
    perm[pos] = i;
    srcS[pos] = src[i];
    dstS[pos] = d;
}

// ---------------- weight prep ----------------
// fp32 [K][N] -> bf16 [N][K], batched over L
__global__ __launch_bounds__(256) void transpose_kernel(
        const float* __restrict__ in, ushortT* __restrict__ out, int K, int N) {
    int per = K * N;
    int total = LL * per;
    int idx = blockIdx.x * 256 + threadIdx.x;
    if (idx >= total) return;
    int l = idx / per, rem = idx - l * per;
    int n = rem / K, k = rem - n * K;
    out[idx] = f2bf(in[(size_t)l * per + (size_t)k * N + n]);
}

__global__ __launch_bounds__(256) void transpose_ee_kernel(
        const float* __restrict__ in, ushortT* __restrict__ out) {
    int idx = blockIdx.x * 256 + threadIdx.x;
    if (idx >= HH * 32) return;
    int n = idx >> 5, k = idx & 31;
    out[idx] = (k < EDIM) ? f2bf(in[k * HH + n]) : (ushortT)0;
}

// w2g[l][n][k] = bf16(nm_w2[l][k][n]*g), nb2g[l][n] = b2*g + bnb,  g = bn_g*inv_std
__global__ __launch_bounds__(256) void bnfold_kernel(
        const float* __restrict__ w2, const float* __restrict__ b2,
        const float* __restrict__ bng, const float* __restrict__ bnb,
        ushortT* __restrict__ w2g, float* __restrict__ nb2g, float inv_std) {
    int idx = blockIdx.x * 256 + threadIdx.x;
    if (idx < LL * HH * HH) {
        int l = idx / (HH * HH), rem = idx - l * (HH * HH);
        int n = rem / HH, k = rem - n * HH;
        w2g[idx] = f2bf(w2[(size_t)l * HH * HH + (size_t)k * HH + n] *
                        bng[l * HH + n] * inv_std);
    }
    if (idx < LL * HH) {
        nb2g[idx] = b2[idx] * bng[idx] * inv_std + bnb[idx];
    }
}

// ---------------- node embed ----------------
__global__ __launch_bounds__(128) void node_embed_kernel(
        const float* __restrict__ x, const float* __restrict__ w,
        const float* __restrict__ b, float* __restrict__ h) {
    __shared__ float xs[NDIM];
    int i = blockIdx.x, j = threadIdx.x;
    if (j < NDIM) xs[j] = x[(size_t)i * NDIM + j];
    __syncthreads();
    float acc = b[j];
#pragma unroll
    for (int k = 0; k < NDIM; ++k) acc += xs[k] * w[k * HH + j];
    h[(size_t)i * HH + j] = acc;
}

// ---------------- GEMM helpers (8 waves 4x2, 128x128 tile, acc[2][4]) ----------
template<int K, int KS, bool HASB>
__device__ inline void gemm_b(const char* aBase, int aStrideB, int aMask,
        const ushortT* __restrict__ wT, const float* __restrict__ bias,
        int wr, int wc, int l15, int lg, f32x4 acc[2][4]) {
#pragma unroll
    for (int ntl = 0; ntl < 4; ++ntl) {
        float bb = HASB ? bias[wc * 64 + ntl * 16 + l15] : 0.f;
        f32x4 iv = {bb, bb, bb, bb};
        acc[0][ntl] = iv;
        acc[1][ntl] = iv;
    }
#pragma unroll
    for (int ks = 0; ks < K / 32; ++ks) {
        int kk = ks * 32 + lg * 8;
        bf16x8 a0 = lds_a(aBase, aStrideB, wr * 32 + l15,      kk * 2, aMask);
        bf16x8 a1 = lds_a(aBase, aStrideB, wr * 32 + 16 + l15, kk * 2, aMask);
#pragma unroll
        for (int ntl = 0; ntl < 4; ++ntl) {
            int n = wc * 64 + ntl * 16 + l15;
            bf16x8 b = *reinterpret_cast<const bf16x8*>(wT + (size_t)n * KS + kk);
            acc[0][ntl] = MFMA16(a0, b, acc[0][ntl]);
            acc[1][ntl] = MFMA16(a1, b, acc[1][ntl]);
        }
    }
}

// G3: acc init from uT (bf16 swz7), A=eT, B = nw1t_l+128 (KS=256)
__device__ inline void gemm_uinit3(const char* aBase, const char* uBase,
        const ushortT* __restrict__ wT,
        int wr, int wc, int l15, int lg, f32x4 acc[2][4]) {
#pragma unroll
    for (int mt = 0; mt < 2; ++mt)
#pragma unroll
        for (int ntl = 0; ntl < 4; ++ntl) {
            int col = wc * 64 + ntl * 16 + l15;
#pragma unroll
            for (int r = 0; r < 4; ++r) {
                int row = wr * 32 + mt * 16 + lg * 4 + r;
                int b = row * 256 + col * 2; b ^= ((row & 7) << 4);
                acc[mt][ntl][r] = bf2f(*reinterpret_cast<const ushortT*>(uBase + b));
            }
        }
#pragma unroll
    for (int ks = 0; ks < 4; ++ks) {
        int kk = ks * 32 + lg * 8;
        bf16x8 a0 = lds_a(aBase, 256, wr * 32 + l15,      kk * 2, 7);
        bf16x8 a1 = lds_a(aBase, 256, wr * 32 + 16 + l15, kk * 2, 7);
#pragma unroll
        for (int ntl = 0; ntl < 4; ++ntl) {
            int n = wc * 64 + ntl * 16 + l15;
            bf16x8 b = *reinterpret_cast<const bf16x8*>(wT + (size_t)n * 256 + kk);
            acc[0][ntl] = MFMA16(a0, b, acc[0][ntl]);
            acc[1][ntl] = MFMA16(a1, b, acc[1][ntl]);
        }
    }
}

__device__ inline void wfrag(char* base, int wr, int wc, int l15, int lg,
                             f32x4 acc[2][4], bool relu) {
#pragma unroll
    for (int mt = 0; mt < 2; ++mt)
#pragma unroll
        for (int ntl = 0; ntl < 4; ++ntl) {
            int col = wc * 64 + ntl * 16 + l15;
#pragma unroll
            for (int r = 0; r < 4; ++r) {
                int row = wr * 32 + mt * 16 + lg * 4 + r;
                int b = row * 256 + col * 2;
                b ^= ((row & 7) << 4);
                float v = acc[mt][ntl][r];
                if (relu) v = fmaxf(v, 0.f);
                *reinterpret_cast<ushortT*>(base + b) = f2bf(v);
            }
        }
}

// ---------------- A: edge kernel ----------------
// embed(l0) -> edge-MLP -> hidden = relu(u[src] + e'@W1b) -> segmented sum by dst
// -> plain stores into partials[slot][node][128], slot = seg(edge) - seg(base[d]) < 3
template<int EMBED, int LASTL>
__global__ __launch_bounds__(512) void edgeA_kernel(
        const ushortT* __restrict__ u, ushortT* __restrict__ e,
        const int* __restrict__ srcS, const int* __restrict__ dstS,
        const int* __restrict__ basep, const int* __restrict__ perm,
        const float* __restrict__ ea,
        const ushortT* __restrict__ eewT, const float* __restrict__ eeb,
        const ushortT* __restrict__ ew1t, const float* __restrict__ eb1,
        const ushortT* __restrict__ ew2t, const float* __restrict__ eb2,
        const ushortT* __restrict__ nw1bt,   // nw1t_l + 128 (KS=256)
        ushortT* __restrict__ partials) {
    __shared__ __align__(16) char eT[128 * 256];
    __shared__ __align__(16) char uT[128 * 256];
    __shared__ int dstx[128], bstartL[128], sidx[128], pidx[128];

    const int e0 = blockIdx.x * 128;
    int V = EE - e0; if (V > 128) V = 128;
    const int tid = threadIdx.x;
    const bf16x8 z8 = {0, 0, 0, 0, 0, 0, 0, 0};

    if (tid < 128) {
        int ii = e0 + tid;
        int d = (ii < EE) ? dstS[ii] : -1;
        dstx[tid] = d;
        bstartL[tid] = (d >= 0) ? basep[d] : 0;
        sidx[tid] = (ii < EE) ? srcS[ii] : 0;
        if (EMBED) pidx[tid] = (ii < EE) ? perm[ii] : 0;
    }
    __syncthreads();

    // stage u[src] -> uT (bf16 swz7), 2048 chunks
#pragma unroll
    for (int s = 0; s < 4; ++s) {
        int idx = tid + s * 512;
        int row = idx >> 4, c8 = (idx & 15) * 8;
        bf16x8 v = *reinterpret_cast<const bf16x8*>(u + (size_t)sidx[row] * HH + c8);
        int b = row * 256 + c8 * 2; b ^= ((row & 7) << 4);
        *reinterpret_cast<bf16x8*>(uT + b) = v;
    }
    if (EMBED) {
        // stage ea[perm] -> eT as [128][32] bf16 swz3 (zero-padded K)
        {
            int row = tid >> 2, q4 = (tid & 3) * 4;
            float4 v = *reinterpret_cast<const float4*>(
                ea + (size_t)pidx[row] * EDIM + q4);
            unsigned long long pack =
                (unsigned long long)f2bf(v.x) |
                ((unsigned long long)f2bf(v.y) << 16) |
                ((unsigned long long)f2bf(v.z) << 32) |
                ((unsigned long long)f2bf(v.w) << 48);
            int b = row * 64 + q4 * 2; b ^= ((row & 3) << 4);
            *reinterpret_cast<unsigned long long*>(eT + b) = pack;
        }
        if (tid < 256) {
            int row = tid >> 1;
            int b = row * 64 + 32 + (tid & 1) * 16; b ^= ((row & 3) << 4);
            *reinterpret_cast<bf16x8*>(eT + b) = z8;
        }
    } else {
        // stage e -> eT (bf16 swz7)
#pragma unroll
        for (int s = 0; s < 4; ++s) {
            int idx = tid + s * 512;
            int row = idx >> 4, c8 = (idx & 15) * 8;
            bf16x8 v = *reinterpret_cast<const bf16x8*>(
                e + (size_t)(e0 + row) * HH + c8);
            int b = row * 256 + c8 * 2; b ^= ((row & 7) << 4);
            *reinterpret_cast<bf16x8*>(eT + b) = v;
        }
    }
    __syncthreads();

    const int wid = tid >> 6, lane = tid & 63;
    const int wr = wid >> 1, wc = wid & 1, l15 = lane & 15, lg = lane >> 4;
    f32x4 acc[2][4];

    if (EMBED) {
        gemm_b<32, 32, true>(eT, 64, 3, eewT, eeb, wr, wc, l15, lg, acc);
        __syncthreads();
        wfrag(eT, wr, wc, l15, lg, acc, false);
        __syncthreads();
    }
    // em1: hid = relu(e @ ew1 + eb1)
    gemm_b<HH, HH, true>(eT, 256, 7, ew1t, eb1, wr, wc, l15, lg, acc);
    __syncthreads();
    wfrag(eT, wr, wc, l15, lg, acc, true);
    __syncthreads();
    // em2: e' = hid @ ew2 + eb2
    gemm_b<HH, HH, true>(eT, 256, 7, ew2t, eb2, wr, wc, l15, lg, acc);
    __syncthreads();
    wfrag(eT, wr, wc, l15, lg, acc, false);
    __syncthreads();
    // e' copy-out (read-only on eT, concurrent with G3 reads)
    if (!LASTL) {
#pragma unroll
        for (int s = 0; s < 4; ++s) {
            int idx = tid + s * 512;
            int row = idx >> 4, c8 = (idx & 15) * 8;
            if (row < V) {
                int b = row * 256 + c8 * 2; b ^= ((row & 7) << 4);
                *reinterpret_cast<bf16x8*>(e + (size_t)(e0 + row) * HH + c8) =
                    *reinterpret_cast<const bf16x8*>(eT + b);
            }
        }
    }
    // G3: hidden = relu(u + e' @ W1b)
    gemm_uinit3(eT, uT, nw1bt, wr, wc, l15, lg, acc);
    __syncthreads();
    wfrag(eT, wr, wc, l15, lg, acc, true);
    __syncthreads();

    // segmented sum of hidden by dst: 128 cols x 4 segs of 32 rows, plain stores
    {
        int col = tid & 127, seg = tid >> 7;
        int r = seg * 32, rend = r + 32;
        float sum = 0.f;
        int dprev = -1, runStart = r;
        for (; r < rend; ++r) {
            int d = dstx[r];
            if (d != dprev) {
                if (dprev >= 0) {
                    int slot = ((e0 + runStart) >> 5) - (bstartL[runStart] >> 5);
                    if (slot < 3)
                        partials[((size_t)slot * NN + dprev) * HH + col] = f2bf(sum);
                }
                sum = 0.f; dprev = d; runStart = r;
            }
            if (d >= 0) {
                int b = r * 256 + col * 2; b ^= ((r & 7) << 4);
                sum += bf2f(*reinterpret_cast<const ushortT*>(eT + b));
            }
        }
        if (dprev >= 0) {
            int slot = ((e0 + runStart) >> 5) - (bstartL[runStart] >> 5);
            if (slot < 3)
                partials[((size_t)slot * NN + dprev) * HH + col] = f2bf(sum);
        }
    }
}

// ---------------- B: node kernel ----------------
// sum partials -> Sigma_hid ; h += Sigma_hid @ w2g + deg*nb2g (in-place) ;
// u_next = bf16(h) @ W1a_next + b1_next
template<int HASU>
__global__ __launch_bounds__(512) void nodeB_kernel(
        const ushortT* __restrict__ partials, const int* __restrict__ basep,
        const ushortT* __restrict__ w2g, const float* __restrict__ nb2g,
        float* __restrict__ h,
        const ushortT* __restrict__ w1tn, const float* __restrict__ b1n,
        ushortT* __restrict__ uOut) {
    __shared__ __align__(16) char sT[128 * 256];
    __shared__ int degx[128];
    const int n0 = blockIdx.x * 128;
    int V = NN - n0; if (V > 128) V = 128;
    const int tid = threadIdx.x;

    __shared__ int basex[128];
    if (tid < 128) {
        int bs = 0, de = 0;
        if (tid < V) {
            int n = n0 + tid;
            bs = basep[n];
            int be = (n + 1 < NN) ? basep[n + 1] : EE;
            de = be - bs;
        }
        basex[tid] = bs;
        degx[tid] = de;
    }
    __syncthreads();

    // Sigma_hid rows -> sT (bf16 swz7)
#pragma unroll
    for (int g = 0; g < 4; ++g) {
        int node = g * 32 + (tid >> 4);
        int c8 = (tid & 15) * 8;
        float s[8] = {0.f, 0.f, 0.f, 0.f, 0.f, 0.f, 0.f, 0.f};
        if (node < V) {
            int bs = basex[node], de = degx[node];
            if (de > 0) {
                int ns = ((bs + de - 1) >> 5) - (bs >> 5) + 1;
                if (ns > 3) ns = 3;
                for (int sl = 0; sl < ns; ++sl) {
                    bf16x8 pv = *reinterpret_cast<const bf16x8*>(
                        partials + ((size_t)sl * NN + n0 + node) * HH + c8);
#pragma unroll
                    for (int j = 0; j < 8; ++j) s[j] += bf2f((ushortT)pv[j]);
                }
            }
        }
        bf16x8 o;
#pragma unroll
        for (int j = 0; j < 8; ++j) o[j] = f2bfs(s[j]);
        int b = node * 256 + c8 * 2; b ^= ((node & 7) << 4);
        *reinterpret_cast<bf16x8*>(sT + b) = o;
    }
    __syncthreads();

    const int wid = tid >> 6, lane = tid & 63;
    const int wr = wid >> 1, wc = wid & 1, l15 = lane & 15, lg = lane >> 4;
    f32x4 acc[2][4];

    // Sigma_msg = Sigma_hid @ w2g ; h_new = h + Sigma_msg + deg*nb2g
    gemm_b<HH, HH, false>(sT, 256, 7, w2g, nullptr, wr, wc, l15, lg, acc);
#pragma unroll
    for (int ntl = 0; ntl < 4; ++ntl) {
        int col = wc * 64 + ntl * 16 + l15;
        float bg = nb2g[col];
#pragma unroll
        for (int mt = 0; mt < 2; ++mt)
#pragma unroll
            for (int r = 0; r < 4; ++r) {
                int row = wr * 32 + mt * 16 + lg * 4 + r;
                if (row < V) {
                    size_t off = (size_t)(n0 + row) * HH + col;
                    float hn = h[off] + acc[mt][ntl][r] + (float)degx[row] * bg;
                    h[off] = hn;
                    acc[mt][ntl][r] = hn;
                } else {
                    acc[mt][ntl][r] = 0.f;
                }
            }
    }
    if (HASU) {
        __syncthreads();
        wfrag(sT, wr, wc, l15, lg, acc, false);   // h_new bf16
        __syncthreads();
        gemm_b<HH, 2 * HH, true>(sT, 256, 7, w1tn, b1n, wr, wc, l15, lg, acc);
        __syncthreads();
        wfrag(sT, wr, wc, l15, lg, acc, false);
        __syncthreads();
#pragma unroll
        for (int s = 0; s < 4; ++s) {
            int idx = tid + s * 512;
            int row = idx >> 4, c8 = (idx & 15) * 8;
            if (row < V) {
                int b = row * 256 + c8 * 2; b ^= ((row & 7) << 4);
                *reinterpret_cast<bf16x8*>(uOut + (size_t)(n0 + row) * HH + c8) =
                    *reinterpret_cast<const bf16x8*>(sT + b);
            }
        }
    }
}

// ---------------- node_pre: u0 = bf16(h) @ W1a_0 + b1_0 ----------------
__global__ __launch_bounds__(512) void node_pre_kernel(
        const float* __restrict__ h, const ushortT* __restrict__ w1t,
        const float* __restrict__ b1, ushortT* __restrict__ uo) {
    __shared__ __align__(16) char sT[128 * 256];
    const int n0 = blockIdx.x * 128;
    int V = NN - n0; if (V > 128) V = 128;
    const int tid = threadIdx.x;
#pragma unroll
    for (int s = 0; s < 4; ++s) {
        int idx = tid + s * 512;
        int row = idx >> 4, c8 = (idx & 15) * 8;
        bf16x8 o = {0, 0, 0, 0, 0, 0, 0, 0};
        if (row < V) {
            const float* hp = h + (size_t)(n0 + row) * HH + c8;
            float4 va = *reinterpret_cast<const float4*>(hp);
            float4 vb = *reinterpret_cast<const float4*>(hp + 4);
            o[0] = f2bfs(va.x); o[1] = f2bfs(va.y); o[2] = f2bfs(va.z); o[3] = f2bfs(va.w);
            o[4] = f2bfs(vb.x); o[5] = f2bfs(vb.y); o[6] = f2bfs(vb.z); o[7] = f2bfs(vb.w);
        }
        int b = row * 256 + c8 * 2; b ^= ((row & 7) << 4);
        *reinterpret_cast<bf16x8*>(sT + b) = o;
    }
    __syncthreads();
    const int wid = tid >> 6, lane = tid & 63;
    const int wr = wid >> 1, wc = wid & 1, l15 = lane & 15, lg = lane >> 4;
    f32x4 acc[2][4];
    gemm_b<HH, 2 * HH, true>(sT, 256, 7, w1t, b1, wr, wc, l15, lg, acc);
    __syncthreads();
    wfrag(sT, wr, wc, l15, lg, acc, false);
    __syncthreads();
#pragma unroll
    for (int s = 0; s < 4; ++s) {
        int idx = tid + s * 512;
        int row = idx >> 4, c8 = (idx & 15) * 8;
        if (row < V) {
            int b = row * 256 + c8 * 2; b ^= ((row & 7) << 4);
            *reinterpret_cast<bf16x8*>(uo + (size_t)(n0 + row) * HH + c8) =
                *reinterpret_cast<const bf16x8*>(sT + b);
        }
    }
}

// ---------------- pool + readout ----------------
__global__ __launch_bounds__(256) void pool_kernel(
        const float* __restrict__ h, const int* __restrict__ batch,
        float* __restrict__ pooled) {
    long long idx = (long long)blockIdx.x * 256 + threadIdx.x;
    if (idx >= (long long)NN * HH) return;
    int i = (int)(idx >> 7), c = (int)(idx & 127);
    atomicAdd(&pooled[(size_t)batch[i] * HH + c], h[idx]);
}

__global__ __launch_bounds__(128) void readout_kernel(
        const float* __restrict__ pooled,
        const float* __restrict__ w1, const float* __restrict__ b1,
        const float* __restrict__ w2, const float* __restrict__ b2,
        float* __restrict__ out) {
    __shared__ float row[HH];
    __shared__ float red[HH];
    int g = blockIdx.x, j = threadIdx.x;
    row[j] = pooled[(size_t)g * HH + j];
    __syncthreads();
    float acc = b1[j];
    for (int k = 0; k < HH; ++k) acc += row[k] * w1[k * HH + j];
    red[j] = fmaxf(acc, 0.f) * w2[j];
    __syncthreads();
    for (int s = 64; s > 0; s >>= 1) {
        if (j < s) red[j] += red[j + s];
        __syncthreads();
    }
    if (j == 0) out[g] = red[0] + b2[0];
}

extern "C" void kernel_launch(void* const* d_in, const int* in_sizes, int n_in,
                              void* d_out, int out_size, void* d_ws, size_t ws_size,
                              hipStream_t stream) {
    const float* x     = (const float*)d_in[0];
    const int*   ei    = (const int*)d_in[1];
    const float* ea    = (const float*)d_in[2];
    const int*   batch = (const int*)d_in[3];
    const float* ne_w  = (const float*)d_in[4];
    const float* ne_b  = (const float*)d_in[5];
    const float* ee_w  = (const float*)d_in[6];
    const float* ee_b  = (const float*)d_in[7];
    const float* nm_w1 = (const float*)d_in[8];
    const float* nm_b1 = (const float*)d_in[9];
    const float* nm_w2 = (const float*)d_in[10];
    const float* nm_b2 = (const float*)d_in[11];
    const float* bn_g  = (const float*)d_in[12];
    const float* bn_b  = (const float*)d_in[13];
    const float* em_w1 = (const float*)d_in[14];
    const float* em_b1 = (const float*)d_in[15];
    const float* em_w2 = (const float*)d_in[16];
    const float* em_b2 = (const float*)d_in[17];
    const float* ro_w1 = (const float*)d_in[18];
    const float* ro_b1 = (const float*)d_in[19];
    const float* ro_w2 = (const float*)d_in[20];
    const float* ro_b2 = (const float*)d_in[21];

    const int* srcp = ei;
    const int* dstp = ei + EE;

    // workspace carve (16B aligned) — total ~212 MB
    char* p = (char*)d_ws;
    float* h = (float*)p;            p += (size_t)NN * HH * 4;
    float* pooled = (float*)p;       p += (size_t)GG * HH * 4;
    ushortT* ebuf = (ushortT*)p;     p += (size_t)EE * HH * 2;
    ushortT* ubuf = (ushortT*)p;     p += (size_t)NN * HH * 2;
    ushortT* partials = (ushortT*)p; p += (size_t)3 * NN * HH * 2;
    ushortT* ew1t = (ushortT*)p;     p += (size_t)LL * HH * HH * 2;
    ushortT* ew2t = (ushortT*)p;     p += (size_t)LL * HH * HH * 2;
    ushortT* nw1t = (ushortT*)p;     p += (size_t)LL * 2 * HH * HH * 2;
    ushortT* w2g  = (ushortT*)p;     p += (size_t)LL * HH * HH * 2;
    float* nb2g   = (float*)p;       p += (size_t)LL * HH * 4;
    ushortT* eewT = (ushortT*)p;     p += (size_t)HH * 32 * 2;
    int* perm   = (int*)p;           p += (size_t)EE * 4;
    int* srcS   = (int*)p;           p += (size_t)EE * 4;
    int* dstS   = (int*)p;           p += (size_t)EE * 4;
    int* counts = (int*)p;           p += (size_t)NN * 4;
    int* basep  = (int*)p;           p += (size_t)NN * 4;
    int* cnt    = (int*)p;           p += (size_t)NN * 4;
    int* bsum   = (int*)p;           p += (size_t)SCAN_NB * 4;
    int* bbase  = (int*)p;           p += (size_t)SCAN_NB * 4;

    // ---- sort edges by dst ----
    hipMemsetAsync(counts, 0, (size_t)NN * 4, stream);
    hipMemsetAsync(cnt, 0, (size_t)NN * 4, stream);
    hist_kernel<<<(EE + 255) / 256, 256, 0, stream>>>(dstp, counts);
    scan_part1<<<SCAN_NB, 256, 0, stream>>>(counts, bsum);
    scan_part2<<<1, 256, 0, stream>>>(bsum, bbase);
    scan_part3<<<SCAN_NB, 256, 0, stream>>>(counts, bbase, basep);
    build_perm_kernel<<<(EE + 255) / 256, 256, 0, stream>>>(
        srcp, dstp, basep, cnt, perm, srcS, dstS);

    // ---- weight prep ----
    const float inv_std = 1.0f / sqrtf(1.0f + 1e-5f);
    transpose_kernel<<<(LL * HH * HH + 255) / 256, 256, 0, stream>>>(em_w1, ew1t, HH, HH);
    transpose_kernel<<<(LL * HH * HH + 255) / 256, 256, 0, stream>>>(em_w2, ew2t, HH, HH);
    transpose_kernel<<<(LL * 2 * HH * HH + 255) / 256, 256, 0, stream>>>(nm_w1, nw1t, 2 * HH, HH);
    bnfold_kernel<<<(LL * HH * HH + 255) / 256, 256, 0, stream>>>(
        nm_w2, nm_b2, bn_g, bn_b, w2g, nb2g, inv_std);
    transpose_ee_kernel<<<(HH * 32 + 255) / 256, 256, 0, stream>>>(ee_w, eewT);

    // ---- node embed + u0 ----
    node_embed_kernel<<<NN, 128, 0, stream>>>(x, ne_w, ne_b, h);
    node_pre_kernel<<<NB2, 512, 0, stream>>>(h, nw1t, nm_b1, ubuf);

    // ---- layers ----
    for (int l = 0; l < LL; ++l) {
        const ushortT* nw1bt = nw1t + (size_t)l * 2 * HH * HH + 128;
        if (l == 0) {
            edgeA_kernel<1, 0><<<NT2, 512, 0, stream>>>(
                ubuf, ebuf, srcS, dstS, basep, perm, ea, eewT, ee_b,
                ew1t + (size_t)l * HH * HH, em_b1 + l * HH,
                ew2t + (size_t)l * HH * HH, em_b2 + l * HH,
                nw1bt, partials);
        } else if (l < LL - 1) {
            edgeA_kernel<0, 0><<<NT2, 512, 0, stream>>>(
                ubuf, ebuf, srcS, dstS, basep, perm, ea, eewT, ee_b,
                ew1t + (size_t)l * HH * HH, em_b1 + l * HH,
                ew2t + (size_t)l * HH * HH, em_b2 + l * HH,
                nw1bt, partials);
        } else {
            edgeA_kernel<0, 1><<<NT2, 512, 0, stream>>>(
                ubuf, ebuf, srcS, dstS, basep, perm, ea, eewT, ee_b,
                ew1t + (size_t)l * HH * HH, em_b1 + l * HH,
                ew2t + (size_t)l * HH * HH, em_b2 + l * HH,
                nw1bt, partials);
        }
        if (l < LL - 1) {
            nodeB_kernel<1><<<NB2, 512, 0, stream>>>(
                partials, basep, w2g + (size_t)l * HH * HH, nb2g + l * HH, h,
                nw1t + (size_t)(l + 1) * 2 * HH * HH, nm_b1 + (l + 1) * HH, ubuf);
        } else {
            nodeB_kernel<0><<<NB2, 512, 0, stream>>>(
                partials, basep, w2g + (size_t)l * HH * HH, nb2g + l * HH, h,
                nw1t, nm_b1, ubuf);
        }
    }

    // ---- pool + readout ----
    hipMemsetAsync(pooled, 0, sizeof(float) * (size_t)GG * HH, stream);
    {
        long long total = (long long)NN * HH;
        pool_kernel<<<(int)((total + 255) / 256), 256, 0, stream>>>(h, batch, pooled);
    }
    readout_kernel<<<GG, 128, 0, stream>>>(pooled, ro_w1, ro_b1, ro_w2, ro_b2,
                                           (float*)d_out);
}